// Round 10
// baseline (1548.329 us; speedup 1.0000x reference)
//
#include <hip/hip_runtime.h>
#include <hip/hip_bf16.h>
#include <hip/hip_fp16.h>
#include <math.h>

constexpr int B = 32, S = 64, T = 64, H = 512, V = 32000;
constexpr int G3 = 3 * H;     // 1536
constexpr int BT = B * T;     // 2048

// ---- workspace layout (float slots) ----
constexpr size_t UAK_OFF    = 0;          // f32 [B*S][512]     1,048,576
constexpr size_t GIE_OFF    = 1048576;    // f32 [B*T][1536]    -> 4,194,304
constexpr size_t KWT2T_OFF  = 4194304;    // u32 [B][32][G3]    -> 5,767,168
constexpr size_t WA2T_OFF   = 5767168;    // u32 [256][512]     -> 5,898,240
constexpr size_t WHH2T_OFF  = 5898240;    // u32 [256][1536]    -> 6,291,456
constexpr size_t ROWIDX_OFF = 6291456;    // 2048 ints          -> 6,293,504
constexpr size_t FLG_OFF    = 6293504;    // 256 ints           -> 6,293,760
constexpr size_t QP_OFF     = 6293760;    // f32 [2][B][8][512] -> 6,555,904
constexpr size_t OWBF_OFF   = 0;          // bf16 [V*H] = 8,192,000 slots; aliases all above
constexpr size_t HALL_OFF   = 8192000;    // f32 [(T+1)*B*H]    -> 9,256,960
constexpr size_t HBF_OFF    = 9256960;    // bf16 [B*T*H]       -> 9,781,248

typedef __attribute__((ext_vector_type(8))) short bf16x8;
typedef __attribute__((ext_vector_type(4))) float f32x4;
typedef __attribute__((ext_vector_type(2))) float f32x2;
typedef __attribute__((ext_vector_type(4))) int i32x4;
typedef _Float16 h2v __attribute__((ext_vector_type(2)));

__device__ __forceinline__ float fast_tanh(float x) {
  float ax = fabsf(x);
  float e = __expf(-2.f * ax);
  float r = (1.f - e) / (1.f + e);
  return x < 0.f ? -r : r;
}
__device__ __forceinline__ float fast_sig(float x) {
  return 1.f / (1.f + __expf(-x));
}
__device__ __forceinline__ unsigned pack_h2(float a, float b) {
  __half2 h = __floats2half2_rn(a, b);
  return *(unsigned*)&h;
}
__device__ __forceinline__ float dot2acc(unsigned w, unsigned h, float c) {
  return __builtin_amdgcn_fdot2(__builtin_bit_cast(h2v, w),
                                __builtin_bit_cast(h2v, h), c, false);
}
__device__ __forceinline__ i32x4 load_coh_i32x4(const int* p) {
  i32x4 v;
  asm volatile("global_load_dwordx4 %0, %1, off sc0 sc1\n\ts_waitcnt vmcnt(0)"
               : "=v"(v) : "v"(p) : "memory");
  return v;
}
__device__ __forceinline__ void store_coh_i32(int* p, int v) {
  asm volatile("global_store_dword %0, %1, off sc0 sc1" :: "v"(p), "v"(v) : "memory");
}
__device__ __forceinline__ void store_coh_f32(float* p, float v) {
  asm volatile("global_store_dword %0, %1, off sc0 sc1" :: "v"(p), "v"(v) : "memory");
}
__device__ __forceinline__ void store_coh_f32x4(float* p, f32x4 v) {
  asm volatile("global_store_dwordx4 %0, %1, off sc0 sc1" :: "v"(p), "v"(v) : "memory");
}
__device__ __forceinline__ int imin(int a, int b) { return a < b ? a : b; }

// -------------------- init: h0, token row indices, flags --------------------
__global__ void k_init(const float* __restrict__ eh, const int* __restrict__ tgt,
                       float* __restrict__ ws) {
  int i = blockIdx.x * 256 + threadIdx.x;      // grid 64*256 = 16384
  if (i < B * H) ws[HALL_OFF + i] = eh[i];
  if (i < BT) {
    int b = i / T, t = i % T;
    ((int*)(ws + ROWIDX_OFF))[i] = (t == 0) ? 0 : tgt[b * T + t - 1];
  }
  if (i < 256) ((int*)(ws + FLG_OFF))[i] = 0;
}

// -------------------- f32 [R][512] -> k-major packed f16x2 [256][R] --------------------
__global__ void k_pack_t(const float* __restrict__ in, unsigned* __restrict__ out, int R) {
  int i = blockIdx.x * 256 + threadIdx.x;
  if (i < R * 256) {
    int r = i >> 8, kk = i & 255;
    float2 v = *(const float2*)&in[(size_t)r * 512 + 2 * kk];
    out[(size_t)kk * R + r] = pack_h2(v.x, v.y);
  }
}

// -------------------- out_w fp32 -> bf16 (runs AFTER recurrence; aliases ws) ----
__global__ void k_conv_outw(const float* __restrict__ w, ushort* __restrict__ o, int n4) {
  int i = blockIdx.x * blockDim.x + threadIdx.x;
  if (i < n4) {
    float4 v = *(const float4*)&w[(size_t)i * 4];
    ushort4 u;
    __hip_bfloat16 h0 = __float2bfloat16(v.x); u.x = *(ushort*)&h0;
    __hip_bfloat16 h1 = __float2bfloat16(v.y); u.y = *(ushort*)&h1;
    __hip_bfloat16 h2 = __float2bfloat16(v.z); u.z = *(ushort*)&h2;
    __hip_bfloat16 h3 = __float2bfloat16(v.w); u.w = *(ushort*)&h3;
    *(ushort4*)&o[(size_t)i * 4] = u;
  }
}

// -------- fp32 tiled GEMM, k-major LDS: C[m*N+n] = A[arow(m),:] . Bw[n,:] + bias[n] --------
__global__ __launch_bounds__(256) void k_gemm_at(
    const float* __restrict__ A, const float* __restrict__ Bw, int ldb,
    const float* __restrict__ bias, float* __restrict__ C,
    const int* __restrict__ rowidx, int N) {
  __shared__ float AsT[32][72];
  __shared__ float BsT[32][72];
  int tid = threadIdx.x;
  int bm = blockIdx.x, bn = blockIdx.y;
  int tr = tid >> 4, tc = tid & 15;
  float acc[4][4] = {};
  for (int k0 = 0; k0 < 512; k0 += 32) {
    __syncthreads();
#pragma unroll
    for (int i = 0; i < 2; i++) {
      int e = tid + i * 256;
      int row = e >> 3, c4 = (e & 7) * 4;
      int ar = bm * 64 + row;
      int arow = rowidx ? rowidx[ar] : ar;
      float4 v = *(const float4*)&A[(size_t)arow * 512 + k0 + c4];
      AsT[c4 + 0][row] = v.x; AsT[c4 + 1][row] = v.y;
      AsT[c4 + 2][row] = v.z; AsT[c4 + 3][row] = v.w;
      float4 u = *(const float4*)&Bw[(size_t)(bn * 64 + row) * ldb + k0 + c4];
      BsT[c4 + 0][row] = u.x; BsT[c4 + 1][row] = u.y;
      BsT[c4 + 2][row] = u.z; BsT[c4 + 3][row] = u.w;
    }
    __syncthreads();
#pragma unroll
    for (int kk = 0; kk < 32; kk++) {
      float4 a4 = *(const float4*)&AsT[kk][tr * 4];
      float4 b4 = *(const float4*)&BsT[kk][tc * 4];
      acc[0][0] += a4.x * b4.x; acc[0][1] += a4.x * b4.y; acc[0][2] += a4.x * b4.z; acc[0][3] += a4.x * b4.w;
      acc[1][0] += a4.y * b4.x; acc[1][1] += a4.y * b4.y; acc[1][2] += a4.y * b4.z; acc[1][3] += a4.y * b4.w;
      acc[2][0] += a4.z * b4.x; acc[2][1] += a4.z * b4.y; acc[2][2] += a4.z * b4.z; acc[2][3] += a4.z * b4.w;
      acc[3][0] += a4.w * b4.x; acc[3][1] += a4.w * b4.y; acc[3][2] += a4.w * b4.z; acc[3][3] += a4.w * b4.w;
    }
  }
#pragma unroll
  for (int i = 0; i < 4; i++) {
    int m = bm * 64 + tr * 4 + i;
#pragma unroll
    for (int j = 0; j < 4; j++) {
      int n = bn * 64 + tc * 4 + j;
      C[(size_t)m * N + n] = acc[i][j] + bias[n];
    }
  }
}

// -------- KWT2T[b][ss][col] (f16x2 over s-pairs) = W_ih_ctx . keys^T --------
__global__ __launch_bounds__(256) void k_gemm_kwt(
    const float* __restrict__ W_ih, const float* __restrict__ keys,
    unsigned* __restrict__ KWT2T) {
  __shared__ float AsT[32][72];
  __shared__ float BsT[32][72];
  int tid = threadIdx.x;
  int bm = blockIdx.x, b = blockIdx.y;
  int tr = tid >> 4, tc = tid & 15;
  float acc[4][4] = {};
  for (int k0 = 0; k0 < 512; k0 += 32) {
    __syncthreads();
#pragma unroll
    for (int i = 0; i < 2; i++) {
      int e = tid + i * 256;
      int row = e >> 3, c4 = (e & 7) * 4;
      float4 v = *(const float4*)&W_ih[(size_t)(bm * 64 + row) * 1024 + 512 + k0 + c4];
      AsT[c4 + 0][row] = v.x; AsT[c4 + 1][row] = v.y;
      AsT[c4 + 2][row] = v.z; AsT[c4 + 3][row] = v.w;
      float4 u = *(const float4*)&keys[(size_t)(b * 64 + row) * 512 + k0 + c4];
      BsT[c4 + 0][row] = u.x; BsT[c4 + 1][row] = u.y;
      BsT[c4 + 2][row] = u.z; BsT[c4 + 3][row] = u.w;
    }
    __syncthreads();
#pragma unroll
    for (int kk = 0; kk < 32; kk++) {
      float4 a4 = *(const float4*)&AsT[kk][tr * 4];
      float4 b4 = *(const float4*)&BsT[kk][tc * 4];
      acc[0][0] += a4.x * b4.x; acc[0][1] += a4.x * b4.y; acc[0][2] += a4.x * b4.z; acc[0][3] += a4.x * b4.w;
      acc[1][0] += a4.y * b4.x; acc[1][1] += a4.y * b4.y; acc[1][2] += a4.y * b4.z; acc[1][3] += a4.y * b4.w;
      acc[2][0] += a4.z * b4.x; acc[2][1] += a4.z * b4.y; acc[2][2] += a4.z * b4.z; acc[2][3] += a4.z * b4.w;
      acc[3][0] += a4.w * b4.x; acc[3][1] += a4.w * b4.y; acc[3][2] += a4.w * b4.z; acc[3][3] += a4.w * b4.w;
    }
  }
  unsigned* KP = KWT2T + (size_t)b * 32 * G3;
#pragma unroll
  for (int i = 0; i < 4; i++) {
    int m = bm * 64 + tr * 4 + i;
    KP[(size_t)(tc * 2 + 0) * G3 + m] = pack_h2(acc[i][0], acc[i][1]);
    KP[(size_t)(tc * 2 + 1) * G3 + m] = pack_h2(acc[i][2], acc[i][3]);
  }
}

// -------------------- persistent recurrence v5: ONE handshake per step --------------------
// 256 WGs x 256 thr. WG w = (b=w>>3, cb=w&7). Per step the WG publishes
// {h-slice[64], q-partial[512] = Wa[:,kslice].h_slice} in ONE flagged exchange
// (plain monotone flag stores, coherent polls). Consumers sum 8 q-partials ->
// full q -> full scores (f16 UAK in LDS, redundant x8) -> local softmax ->
// gh (global coalesced f16) overlapped with score VALU -> gic (global f16 KWT)
// -> GRU -> publish next. QP depth-2 rotation read coherently (spread<=1 proof:
// a WG at step t+1 needs all flags>=t+2, so every peer finished reading QP[t&1]).
__global__ __launch_bounds__(256, 1) void k_recur(
    const float* __restrict__ Wa_b, const float* __restrict__ Va_w,
    const float* __restrict__ Va_b, const float* __restrict__ b_hh,
    const unsigned* __restrict__ WA2T, const unsigned* __restrict__ WHH2T,
    float* __restrict__ ws, float* __restrict__ attn_out) {
  const int w = blockIdx.x;
  const int tid = threadIdx.x;
  const int b = w >> 3, cb = w & 7;
  const int j0 = cb * 64;
  int* flg = (int*)(ws + FLG_OFF) + b * 8;
  float* QP = ws + QP_OFF;
  __hip_bfloat16* HBF = (__hip_bfloat16*)(ws + HBF_OFF);
  const float* GIE = ws + GIE_OFF;
  const unsigned* KWT2T = (const unsigned*)(ws + KWT2T_OFF);

  __shared__ unsigned sWa[32 * 512];      // 64 KB  [kkl][j] Wa k-slice f16x2
  __shared__ unsigned sUA[64 * 260];      // 65 KB  [s][kkpair] UAK f16x2, pad 260
  __shared__ float sh[512];
  __shared__ unsigned sH2[256];
  __shared__ unsigned sHn2[32];
  __shared__ float sq[512];
  __shared__ float sVa[512];
  __shared__ float spp[64][5];
  __shared__ float swt[64];
  __shared__ unsigned sW2[32];
  __shared__ float sga[4][64];
  __shared__ float shn[64];

  // ---- one-time staging ----
  for (int idx = tid; idx < 32 * 512; idx += 256)
    sWa[idx] = WA2T[(size_t)(cb * 32 + (idx >> 9)) * 512 + (idx & 511)];
  for (int idx = tid; idx < 64 * 256; idx += 256) {
    int s = idx >> 8, kk = idx & 255;
    float2 u = *(const float2*)&ws[UAK_OFF + ((size_t)(b * 64 + s)) * 512 + 2 * kk];
    sUA[s * 260 + kk] = pack_h2(u.x, u.y);
  }
  sVa[tid] = Va_w[tid];
  sVa[tid + 256] = Va_w[tid + 256];
  const float va_b = Va_b[0];
  const float wab0 = Wa_b[2 * tid], wab1 = Wa_b[2 * tid + 1];
  float bhh = 0.f;
  if (tid < 192) bhh = b_hh[(tid >> 6) * 512 + j0 + (tid & 63)];
  __syncthreads();

  // ---- prologue: publish q-partial for step 0 from own h0 slice ----
  if (tid < 64) shn[tid] = ws[HALL_OFF + (size_t)b * 512 + j0 + tid];
  if (tid < 32) sHn2[tid] = pack_h2(shn[2 * tid], shn[2 * tid + 1]);  // wave 0, in-order
  __syncthreads();
  {
    float a = 0.f, c = 0.f;
#pragma unroll
    for (int kkl = 0; kkl < 32; kkl++) {
      unsigned hp = sHn2[kkl];
      a = dot2acc(sWa[kkl * 512 + tid], hp, a);
      c = dot2acc(sWa[kkl * 512 + tid + 256], hp, c);
    }
    float* qdst = QP + ((size_t)b * 8 + cb) * 512;   // parity 0
    store_coh_f32(qdst + tid, a);
    store_coh_f32(qdst + tid + 256, c);
  }
  asm volatile("s_waitcnt vmcnt(0)" ::: "memory");
  __syncthreads();
  if (tid == 0) store_coh_i32(&flg[cb], 1);

  for (int t = 0; t < T; ++t) {
    // ---- 1. wait all 8 publishes for step t ----
    if (tid == 0) {
      while (true) {
        i32x4 f0 = load_coh_i32x4(flg);
        i32x4 f1 = load_coh_i32x4(flg + 4);
        int m = imin(imin(imin(f0.x, f0.y), imin(f0.z, f0.w)),
                     imin(imin(f1.x, f1.y), imin(f1.z, f1.w)));
        if (m >= t + 1) break;
        __builtin_amdgcn_s_sleep(1);
      }
    }
    __syncthreads();
    // ---- 2. stage h_t (rotating, first-touch fresh) + GIE prefetch ----
    const float* hcur = ws + HALL_OFF + (size_t)t * (B * 512) + b * 512;
    sh[tid] = hcur[tid];
    sh[tid + 256] = hcur[tid + 256];
    float gival = 0.f;
    if (tid < 192)
      gival = GIE[((size_t)b * T + t) * G3 + (tid >> 6) * 512 + j0 + (tid & 63)];
    __syncthreads();
    sH2[tid & 255] = (tid < 256) ? pack_h2(sh[2 * tid], sh[2 * tid + 1]) : 0u;
    __syncthreads();
    // ---- 3. coherent QP batch load -> full q ----
    f32x2 qv[8];
    {
      const float* qbase = QP + (((size_t)(t & 1) * B + b) * 8) * 512 + 2 * tid;
#pragma unroll
      for (int i = 0; i < 8; i++)
        asm volatile("global_load_dwordx2 %0, %1, off sc0 sc1"
                     : "=v"(qv[i]) : "v"(qbase + (size_t)i * 512) : "memory");
      asm volatile("s_waitcnt vmcnt(0)" ::: "memory");
      __builtin_amdgcn_sched_barrier(0);
      float s0 = ((qv[0].x + qv[1].x) + (qv[2].x + qv[3].x))
               + ((qv[4].x + qv[5].x) + (qv[6].x + qv[7].x));
      float s1 = ((qv[0].y + qv[1].y) + (qv[2].y + qv[3].y))
               + ((qv[4].y + qv[5].y) + (qv[6].y + qv[7].y));
      sq[2 * tid] = s0 + wab0;
      sq[2 * tid + 1] = s1 + wab1;
    }
    __syncthreads();
    // ---- 4. gh (L2-bound) + full scores (VALU) in one region ----
    float gh = 0.f;
    if (tid < 192) {
      int gate = tid >> 6, lane = tid & 63;
      const unsigned* wp = WHH2T + gate * 512 + j0 + lane;
      float g0 = 0.f, g1 = 0.f;
#pragma unroll 8
      for (int kk = 0; kk < 256; kk += 2) {
        g0 = dot2acc(wp[(size_t)kk * 1536], sH2[kk], g0);
        g1 = dot2acc(wp[(size_t)(kk + 1) * 1536], sH2[kk + 1], g1);
      }
      gh = g0 + g1 + bhh;
    }
    {
      int s = tid >> 2, jc = tid & 3;
      const unsigned* ur = &sUA[s * 260 + jc * 64];
      const float* qq = sq + jc * 128;
      const float* vv = sVa + jc * 128;
      float a0 = 0.f, a1 = 0.f;
#pragma unroll 4
      for (int kk = 0; kk < 64; kk++) {
        unsigned u = ur[kk];
        __half2 hu = *(__half2*)&u;
        a0 += vv[2 * kk] * fast_tanh(qq[2 * kk] + __low2float(hu));
        a1 += vv[2 * kk + 1] * fast_tanh(qq[2 * kk + 1] + __high2float(hu));
      }
      spp[s][jc] = a0 + a1;
    }
    __syncthreads();
    // ---- 5. local softmax (identical across the 8 WGs of b) ----
    if (tid < 64) {
      float v = spp[tid][0] + spp[tid][1] + spp[tid][2] + spp[tid][3] + va_b;
      float m = v;
      for (int o = 32; o; o >>= 1) m = fmaxf(m, __shfl_xor(m, o, 64));
      float e = __expf(v - m);
      float su = e;
      for (int o = 32; o; o >>= 1) su += __shfl_xor(su, o, 64);
      float wt = e / su;
      swt[tid] = wt;
      if (cb == 0) attn_out[((size_t)b * T + t) * S + tid] = wt;
      float w0 = __shfl(wt, 2 * (tid & 31), 64);
      float w1 = __shfl(wt, 2 * (tid & 31) + 1, 64);
      if (tid < 32) sW2[tid] = pack_h2(w0, w1);
    }
    __syncthreads();
    // ---- 6. gic (global f16 KWT, coalesced) + combine ----
    if (tid < 192) {
      int gate = tid >> 6, lane = tid & 63;
      int col = gate * 512 + j0 + lane;
      const unsigned* kp = KWT2T + (size_t)b * 32 * G3 + col;
      float c0 = 0.f, c1 = 0.f;
#pragma unroll 8
      for (int ss = 0; ss < 32; ss += 2) {
        c0 = dot2acc(kp[(size_t)ss * G3], sW2[ss], c0);
        c1 = dot2acc(kp[(size_t)(ss + 1) * G3], sW2[ss + 1], c1);
      }
      float gi = gival + c0 + c1;
      if (gate == 0) sga[0][lane] = gi + gh;
      else if (gate == 1) sga[1][lane] = gi + gh;
      else { sga[2][lane] = gi; sga[3][lane] = gh; }
    }
    __syncthreads();
    // ---- 7. GRU update (wave 0) + pack own new h-slice ----
    if (tid < 64) {
      float r = fast_sig(sga[0][tid]);
      float z = fast_sig(sga[1][tid]);
      float n = fast_tanh(sga[2][tid] + r * sga[3][tid]);
      float hn = (1.f - z) * n + z * sh[j0 + tid];
      shn[tid] = hn;
      HBF[((size_t)b * T + t) * 512 + j0 + tid] = __float2bfloat16(hn);
    }
    if (tid < 32) sHn2[tid] = pack_h2(shn[2 * tid], shn[2 * tid + 1]);  // wave 0, in-order
    __syncthreads();
    // ---- 8. publish h-slice + next q-partial, flag = t+2 ----
    if (tid < 16)
      store_coh_f32x4(ws + HALL_OFF + (size_t)(t + 1) * (B * 512) + b * 512 + j0 + tid * 4,
                      *(f32x4*)&shn[tid * 4]);
    if (t < T - 1) {
      float a = 0.f, c = 0.f;
#pragma unroll
      for (int kkl = 0; kkl < 32; kkl++) {
        unsigned hp = sHn2[kkl];
        a = dot2acc(sWa[kkl * 512 + tid], hp, a);
        c = dot2acc(sWa[kkl * 512 + tid + 256], hp, c);
      }
      float* qdst = QP + (((size_t)((t + 1) & 1) * B + b) * 8 + cb) * 512;
      store_coh_f32(qdst + tid, a);
      store_coh_f32(qdst + tid + 256, c);
    }
    asm volatile("s_waitcnt vmcnt(0)" ::: "memory");
    __syncthreads();
    if (tid == 0 && t < T - 1) store_coh_i32(&flg[cb], t + 2);
  }
}

// -------------------- bf16 MFMA out-projection: [2048,512] x [32000,512]^T --------------------
__global__ __launch_bounds__(256) void k_outgemm(
    const __hip_bfloat16* __restrict__ Abf, const __hip_bfloat16* __restrict__ Bbf,
    const float* __restrict__ bias, float* __restrict__ Cmat) {
  constexpr int LDT = 40;
  __shared__ __align__(16) short As[128 * LDT];
  __shared__ __align__(16) short Bs[128 * LDT];
  int bm = blockIdx.y, bn = blockIdx.x;
  int tid = threadIdx.x;
  int lane = tid & 63, wid = tid >> 6;
  int wm = wid >> 1, wn = wid & 1;
  f32x4 acc[4][4] = {};
  int srow = tid >> 1, shalf = tid & 1;
  for (int k0 = 0; k0 < 512; k0 += 32) {
    const float4* ga = (const float4*)&Abf[(size_t)(bm * 128 + srow) * 512 + k0 + shalf * 16];
    const float4* gb = (const float4*)&Bbf[(size_t)(bn * 128 + srow) * 512 + k0 + shalf * 16];
    float4 va0 = ga[0], va1 = ga[1];
    float4 vb0 = gb[0], vb1 = gb[1];
    __syncthreads();
    *(float4*)&As[srow * LDT + shalf * 16] = va0;
    *(float4*)&As[srow * LDT + shalf * 16 + 8] = va1;
    *(float4*)&Bs[srow * LDT + shalf * 16] = vb0;
    *(float4*)&Bs[srow * LDT + shalf * 16 + 8] = vb1;
    __syncthreads();
    int kc = lane >> 4, rl = lane & 15;
    bf16x8 af[4], bfv[4];
#pragma unroll
    for (int f = 0; f < 4; f++) {
      af[f] = *(const bf16x8*)&As[(wm * 64 + f * 16 + rl) * LDT + kc * 8];
      bfv[f] = *(const bf16x8*)&Bs[(wn * 64 + f * 16 + rl) * LDT + kc * 8];
    }
#pragma unroll
    for (int i = 0; i < 4; i++)
#pragma unroll
      for (int j = 0; j < 4; j++)
        acc[i][j] = __builtin_amdgcn_mfma_f32_16x16x32_bf16(af[i], bfv[j], acc[i][j], 0, 0, 0);
  }
  int cl = lane & 15, rg = lane >> 4;
#pragma unroll
  for (int i = 0; i < 4; i++) {
    int m = bm * 128 + wm * 64 + i * 16 + rg * 4;
#pragma unroll
    for (int j = 0; j < 4; j++) {
      int n = bn * 128 + wn * 64 + j * 16 + cl;
      float bv = bias[n];
#pragma unroll
      for (int r = 0; r < 4; r++)
        Cmat[(size_t)(m + r) * V + n] = acc[i][j][r] + bv;
    }
  }
}

// -------------------- in-place log_softmax (online stats, 4 indep accumulators) ----
__global__ __launch_bounds__(256) void k_logsoftmax(float* __restrict__ Cmat) {
  int row = blockIdx.x;
  float* p = Cmat + (size_t)row * V;
  int tid = threadIdx.x;
  __shared__ float sm[4], ss[4];
  float m0 = -1e30f, m1 = -1e30f, m2 = -1e30f, m3 = -1e30f;
  float s0 = 0.f, s1 = 0.f, s2 = 0.f, s3 = 0.f;
  for (int i = tid * 4; i < V; i += 1024) {
    float4 v = *(const float4*)&p[i];
    float n0 = fmaxf(m0, v.x); s0 = s0 * __expf(m0 - n0) + __expf(v.x - n0); m0 = n0;
    float n1 = fmaxf(m1, v.y); s1 = s1 * __expf(m1 - n1) + __expf(v.y - n1); m1 = n1;
    float n2 = fmaxf(m2, v.z); s2 = s2 * __expf(m2 - n2) + __expf(v.z - n2); m2 = n2;
    float n3 = fmaxf(m3, v.w); s3 = s3 * __expf(m3 - n3) + __expf(v.w - n3); m3 = n3;
  }
  float m = fmaxf(fmaxf(m0, m1), fmaxf(m2, m3));
  float s = s0 * __expf(m0 - m) + s1 * __expf(m1 - m)
          + s2 * __expf(m2 - m) + s3 * __expf(m3 - m);
  for (int o = 32; o; o >>= 1) {
    float om = __shfl_xor(m, o, 64), os = __shfl_xor(s, o, 64);
    float nm = fmaxf(m, om);
    s = s * __expf(m - nm) + os * __expf(om - nm);
    m = nm;
  }
  if ((tid & 63) == 0) { sm[tid >> 6] = m; ss[tid >> 6] = s; }
  __syncthreads();
  float M = fmaxf(fmaxf(sm[0], sm[1]), fmaxf(sm[2], sm[3]));
  float Ssum = ss[0] * __expf(sm[0] - M) + ss[1] * __expf(sm[1] - M)
             + ss[2] * __expf(sm[2] - M) + ss[3] * __expf(sm[3] - M);
  float lse = M + __logf(Ssum);
  for (int i = tid * 4; i < V; i += 1024) {
    float4 v = *(const float4*)&p[i];
    v.x -= lse; v.y -= lse; v.z -= lse; v.w -= lse;
    *(float4*)&p[i] = v;
  }
}

__global__ void k_copy_ht(const float* __restrict__ hsrc, float* __restrict__ o) {
  int i = blockIdx.x * 256 + threadIdx.x;
  if (i < B * H) o[i] = hsrc[i];
}

extern "C" void kernel_launch(void* const* d_in, const int* in_sizes, int n_in,
                              void* d_out, int out_size, void* d_ws, size_t ws_size,
                              hipStream_t stream) {
  (void)in_sizes; (void)n_in; (void)out_size; (void)ws_size;
  const float* keys = (const float*)d_in[0];
  const float* ehid = (const float*)d_in[1];
  const int* tgt    = (const int*)d_in[2];
  const float* emb  = (const float*)d_in[4];
  const float* Wa_w = (const float*)d_in[5];
  const float* Wa_b = (const float*)d_in[6];
  const float* Ua_w = (const float*)d_in[7];
  const float* Ua_b = (const float*)d_in[8];
  const float* Va_w = (const float*)d_in[9];
  const float* Va_b = (const float*)d_in[10];
  const float* W_ih = (const float*)d_in[11];
  const float* W_hh = (const float*)d_in[12];
  const float* b_ih = (const float*)d_in[13];
  const float* b_hh = (const float*)d_in[14];
  const float* out_w = (const float*)d_in[15];
  const float* out_b = (const float*)d_in[16];
  float* ws = (float*)d_ws;
  float* out = (float*)d_out;
  float* logits = out;                              // [B,T,V]
  float* ht_out = out + (size_t)B * T * V;          // [1,B,H]
  float* attn_out = ht_out + (size_t)B * H;         // [B,T,S]

  hipLaunchKernelGGL(k_init, dim3(64), dim3(256), 0, stream, ehid, tgt, ws);
  // Ua_keys = keys @ Ua_w.T + Ua_b -> [B*S][512]
  hipLaunchKernelGGL(k_gemm_at, dim3(32, 8), dim3(256), 0, stream,
                     keys, Ua_w, 512, Ua_b, ws + UAK_OFF, (const int*)nullptr, 512);
  // Gi_e = emb[tokens] @ W_ih[:, :512].T + b_ih -> [B*T][1536]
  hipLaunchKernelGGL(k_gemm_at, dim3(32, 24), dim3(256), 0, stream,
                     emb, W_ih, 1024, b_ih, ws + GIE_OFF, (const int*)(ws + ROWIDX_OFF), G3);
  // KWT2T f16x2 [b][ss][col]
  hipLaunchKernelGGL(k_gemm_kwt, dim3(24, 32), dim3(256), 0, stream,
                     W_ih, keys, (unsigned*)(ws + KWT2T_OFF));
  // k-major packed f16x2 weights
  hipLaunchKernelGGL(k_pack_t, dim3(512), dim3(256), 0, stream,
                     Wa_w, (unsigned*)(ws + WA2T_OFF), 512);
  hipLaunchKernelGGL(k_pack_t, dim3(1536), dim3(256), 0, stream,
                     W_hh, (unsigned*)(ws + WHH2T_OFF), 1536);
  // persistent recurrence: ONE handshake per step
  hipLaunchKernelGGL(k_recur, dim3(256), dim3(256), 0, stream,
                     Wa_b, Va_w, Va_b, b_hh,
                     (const unsigned*)(ws + WA2T_OFF), (const unsigned*)(ws + WHH2T_OFF),
                     ws, attn_out);
  hipLaunchKernelGGL(k_copy_ht, dim3(64), dim3(256), 0, stream,
                     ws + HALL_OFF + (size_t)T * B * H, ht_out);
  // bf16 out_w copy into the (now dead) precompute region
  hipLaunchKernelGGL(k_conv_outw, dim3((V * H / 4 + 255) / 256), dim3(256), 0, stream,
                     out_w, (ushort*)(ws + OWBF_OFF), V * H / 4);
  hipLaunchKernelGGL(k_outgemm, dim3(250, 16), dim3(256), 0, stream,
                     (const __hip_bfloat16*)(ws + HBF_OFF),
                     (const __hip_bfloat16*)(ws + OWBF_OFF), out_b, logits);
  hipLaunchKernelGGL(k_logsoftmax, dim3(BT), dim3(256), 0, stream, logits);
}

// Round 11
// 1421.986 us; speedup vs baseline: 1.0888x; 1.0888x over previous
//
#include <hip/hip_runtime.h>
#include <hip/hip_bf16.h>
#include <hip/hip_fp16.h>
#include <math.h>

constexpr int B = 32, S = 64, T = 64, H = 512, V = 32000;
constexpr int G3 = 3 * H;     // 1536
constexpr int BT = B * T;     // 2048

// ---- workspace layout (float slots) ----
constexpr size_t UAK_OFF    = 0;          // f32 [B*S][512]     1,048,576
constexpr size_t GIE_OFF    = 1048576;    // f32 [B*T][1536]    3,145,728 -> 4,194,304
constexpr size_t KWT_OFF    = 4194304;    // f32 [B][G3][64]    3,145,728 -> 7,340,032
constexpr size_t WA2T_OFF   = 7340032;    // u32 [256][512]       131,072 -> 7,471,104
constexpr size_t WHH2T_OFF  = 7471104;    // u32 [256][1536]      393,216 -> 7,864,320
constexpr size_t ROWIDX_OFF = 7864320;    // 2048 ints            -> 7,866,368
constexpr size_t SCP_OFF    = 7866368;    // f32 [B][8][64]        16,384 -> 7,882,752
constexpr size_t FLG_OFF    = 7882752;    // T*64 ints              4,096 -> 7,886,848
constexpr size_t OWBF_OFF   = 0;          // bf16 [V*H] = 8,192,000 slots; aliases all
                                          // of the above (dead after k_recur)
constexpr size_t HALL_OFF   = 8192000;    // f32 [(T+1)*B*H]    1,064,960 -> 9,256,960
constexpr size_t STATS_OFF  = 8192000;    // f32 [2048][512] = 1,048,576; reuses HALL
                                          // (dead after k_copy_ht)
constexpr size_t HBF_OFF    = 9256960;    // bf16 [B*T*H] 524,288 slots  -> 9,781,248

typedef __attribute__((ext_vector_type(8))) short bf16x8;
typedef __attribute__((ext_vector_type(4))) float f32x4;
typedef _Float16 h2v __attribute__((ext_vector_type(2)));

__device__ __forceinline__ float fast_tanh(float x) {
  float ax = fabsf(x);
  float e = __expf(-2.f * ax);
  float r = (1.f - e) / (1.f + e);
  return x < 0.f ? -r : r;
}
__device__ __forceinline__ float fast_sig(float x) {
  return 1.f / (1.f + __expf(-x));
}
__device__ __forceinline__ unsigned pack_h2(float a, float b) {
  __half2 h = __floats2half2_rn(a, b);
  return *(unsigned*)&h;
}
__device__ __forceinline__ float dot2acc(unsigned w, unsigned h, float c) {
  return __builtin_amdgcn_fdot2(__builtin_bit_cast(h2v, w),
                                __builtin_bit_cast(h2v, h), c, false);
}
__device__ __forceinline__ int load_coh_i32(const int* p) {
  int v;
  asm volatile("global_load_dword %0, %1, off sc0 sc1\n\ts_waitcnt vmcnt(0)"
               : "=v"(v) : "v"(p) : "memory");
  return v;
}
__device__ __forceinline__ f32x4 load_coh_f32x4(const float* p) {
  f32x4 v;
  asm volatile("global_load_dwordx4 %0, %1, off sc0 sc1\n\ts_waitcnt vmcnt(0)"
               : "=v"(v) : "v"(p) : "memory");
  return v;
}
__device__ __forceinline__ void store_coh_f32x4(float* p, f32x4 v) {
  asm volatile("global_store_dwordx4 %0, %1, off sc0 sc1" :: "v"(p), "v"(v) : "memory");
}

// -------------------- init: h0, token row indices, flags --------------------
__global__ void k_init(const float* __restrict__ eh, const int* __restrict__ tgt,
                       float* __restrict__ ws) {
  int i = blockIdx.x * 256 + threadIdx.x;      // grid 64*256 = 16384
  if (i < B * H) ws[HALL_OFF + i] = eh[i];
  if (i < BT) {
    int b = i / T, t = i % T;
    ((int*)(ws + ROWIDX_OFF))[i] = (t == 0) ? 0 : tgt[b * T + t - 1];
  }
  if (i < T * 64) ((int*)(ws + FLG_OFF))[i] = 0;
}

// -------------------- f32 [R][512] -> k-major packed f16x2 [256][R] --------------------
__global__ void k_pack_t(const float* __restrict__ in, unsigned* __restrict__ out, int R) {
  int i = blockIdx.x * 256 + threadIdx.x;
  if (i < R * 256) {
    int r = i >> 8, kk = i & 255;
    float2 v = *(const float2*)&in[(size_t)r * 512 + 2 * kk];
    out[(size_t)kk * R + r] = pack_h2(v.x, v.y);
  }
}

// -------------------- out_w fp32 -> bf16 (runs AFTER recurrence; aliases ws) ----
__global__ void k_conv_outw(const float* __restrict__ w, ushort* __restrict__ o, int n4) {
  int i = blockIdx.x * blockDim.x + threadIdx.x;
  if (i < n4) {
    float4 v = *(const float4*)&w[(size_t)i * 4];
    ushort4 u;
    __hip_bfloat16 h0 = __float2bfloat16(v.x); u.x = *(ushort*)&h0;
    __hip_bfloat16 h1 = __float2bfloat16(v.y); u.y = *(ushort*)&h1;
    __hip_bfloat16 h2 = __float2bfloat16(v.z); u.z = *(ushort*)&h2;
    __hip_bfloat16 h3 = __float2bfloat16(v.w); u.w = *(ushort*)&h3;
    *(ushort4*)&o[(size_t)i * 4] = u;
  }
}

// -------- fp32 tiled GEMM, k-major LDS: C[m*N+n] = A[arow(m),:] . Bw[n,:] + bias[n] --------
__global__ __launch_bounds__(256) void k_gemm_at(
    const float* __restrict__ A, const float* __restrict__ Bw, int ldb,
    const float* __restrict__ bias, float* __restrict__ C,
    const int* __restrict__ rowidx, int N) {
  __shared__ float AsT[32][72];
  __shared__ float BsT[32][72];
  int tid = threadIdx.x;
  int bm = blockIdx.x, bn = blockIdx.y;
  int tr = tid >> 4, tc = tid & 15;
  float acc[4][4] = {};
  for (int k0 = 0; k0 < 512; k0 += 32) {
    __syncthreads();
#pragma unroll
    for (int i = 0; i < 2; i++) {
      int e = tid + i * 256;
      int row = e >> 3, c4 = (e & 7) * 4;
      int ar = bm * 64 + row;
      int arow = rowidx ? rowidx[ar] : ar;
      float4 v = *(const float4*)&A[(size_t)arow * 512 + k0 + c4];
      AsT[c4 + 0][row] = v.x; AsT[c4 + 1][row] = v.y;
      AsT[c4 + 2][row] = v.z; AsT[c4 + 3][row] = v.w;
      float4 u = *(const float4*)&Bw[(size_t)(bn * 64 + row) * ldb + k0 + c4];
      BsT[c4 + 0][row] = u.x; BsT[c4 + 1][row] = u.y;
      BsT[c4 + 2][row] = u.z; BsT[c4 + 3][row] = u.w;
    }
    __syncthreads();
#pragma unroll
    for (int kk = 0; kk < 32; kk++) {
      float4 a4 = *(const float4*)&AsT[kk][tr * 4];
      float4 b4 = *(const float4*)&BsT[kk][tc * 4];
      acc[0][0] += a4.x * b4.x; acc[0][1] += a4.x * b4.y; acc[0][2] += a4.x * b4.z; acc[0][3] += a4.x * b4.w;
      acc[1][0] += a4.y * b4.x; acc[1][1] += a4.y * b4.y; acc[1][2] += a4.y * b4.z; acc[1][3] += a4.y * b4.w;
      acc[2][0] += a4.z * b4.x; acc[2][1] += a4.z * b4.y; acc[2][2] += a4.z * b4.z; acc[2][3] += a4.z * b4.w;
      acc[3][0] += a4.w * b4.x; acc[3][1] += a4.w * b4.y; acc[3][2] += a4.w * b4.z; acc[3][3] += a4.w * b4.w;
    }
  }
#pragma unroll
  for (int i = 0; i < 4; i++) {
    int m = bm * 64 + tr * 4 + i;
#pragma unroll
    for (int j = 0; j < 4; j++) {
      int n = bn * 64 + tc * 4 + j;
      C[(size_t)m * N + n] = acc[i][j] + bias[n];
    }
  }
}

// -------- KWT[b, col, s] = sum_k W_ih[col, 512+k] * keys[b*64+s, k]  (f32) --------
__global__ __launch_bounds__(256) void k_gemm_kwt(
    const float* __restrict__ W_ih, const float* __restrict__ keys,
    float* __restrict__ KWT) {
  __shared__ float AsT[32][72];
  __shared__ float BsT[32][72];
  int tid = threadIdx.x;
  int bm = blockIdx.x, b = blockIdx.y;
  int tr = tid >> 4, tc = tid & 15;
  float acc[4][4] = {};
  for (int k0 = 0; k0 < 512; k0 += 32) {
    __syncthreads();
#pragma unroll
    for (int i = 0; i < 2; i++) {
      int e = tid + i * 256;
      int row = e >> 3, c4 = (e & 7) * 4;
      float4 v = *(const float4*)&W_ih[(size_t)(bm * 64 + row) * 1024 + 512 + k0 + c4];
      AsT[c4 + 0][row] = v.x; AsT[c4 + 1][row] = v.y;
      AsT[c4 + 2][row] = v.z; AsT[c4 + 3][row] = v.w;
      float4 u = *(const float4*)&keys[(size_t)(b * 64 + row) * 512 + k0 + c4];
      BsT[c4 + 0][row] = u.x; BsT[c4 + 1][row] = u.y;
      BsT[c4 + 2][row] = u.z; BsT[c4 + 3][row] = u.w;
    }
    __syncthreads();
#pragma unroll
    for (int kk = 0; kk < 32; kk++) {
      float4 a4 = *(const float4*)&AsT[kk][tr * 4];
      float4 b4 = *(const float4*)&BsT[kk][tc * 4];
      acc[0][0] += a4.x * b4.x; acc[0][1] += a4.x * b4.y; acc[0][2] += a4.x * b4.z; acc[0][3] += a4.x * b4.w;
      acc[1][0] += a4.y * b4.x; acc[1][1] += a4.y * b4.y; acc[1][2] += a4.y * b4.z; acc[1][3] += a4.y * b4.w;
      acc[2][0] += a4.z * b4.x; acc[2][1] += a4.z * b4.y; acc[2][2] += a4.z * b4.z; acc[2][3] += a4.z * b4.w;
      acc[3][0] += a4.w * b4.x; acc[3][1] += a4.w * b4.y; acc[3][2] += a4.w * b4.z; acc[3][3] += a4.w * b4.w;
    }
  }
#pragma unroll
  for (int i = 0; i < 4; i++) {
    int m = bm * 64 + tr * 4 + i;
#pragma unroll
    for (int j = 0; j < 4; j++)
      KWT[((size_t)b * G3 + m) * 64 + tc * 4 + j] = acc[i][j];
  }
}

// -------------------- persistent recurrence (r9 proven: 1010 us) --------------------
__global__ __launch_bounds__(256) void k_recur(
    const float* __restrict__ Wa_b, const float* __restrict__ Va_w,
    const float* __restrict__ Va_b, const float* __restrict__ b_hh,
    const unsigned* __restrict__ WA2T, const unsigned* __restrict__ WHH2T,
    float* __restrict__ ws, float* __restrict__ attn_out) {
  const int w = blockIdx.x;
  const int tid = threadIdx.x;
  const int b = w >> 3, cb = w & 7;
  const int j0 = cb * 64;
  int* flg = (int*)(ws + FLG_OFF);
  __hip_bfloat16* HBF = (__hip_bfloat16*)(ws + HBF_OFF);
  const float* GIE = ws + GIE_OFF;
  float* SCP = ws + SCP_OFF;

  __shared__ float sKWT[192][68];   // 52.2 KB
  __shared__ float sUAK[64][68];    // 17.4 KB
  __shared__ float sh[512];
  __shared__ unsigned sH2[256];
  __shared__ float sq[64];
  __shared__ float qp[64][5];
  __shared__ float spp[64][5];
  __shared__ float sps[64];
  __shared__ float scg[8][64];
  __shared__ float swt[64];
  __shared__ float sga[4][64];
  __shared__ float shn[64];
  __shared__ float sVa[64], sWab[64], sBhh[192];

  // ---- one-time staging ----
#pragma unroll
  for (int g = 0; g < 3; g++) {
    int jl = tid >> 2, part = tid & 3;
    const float* src = ws + KWT_OFF + ((size_t)b * G3 + g * 512 + j0 + jl) * 64 + part * 16;
    float* dst = &sKWT[g * 64 + jl][part * 16];
#pragma unroll
    for (int i = 0; i < 16; i += 4) *(float4*)&dst[i] = *(const float4*)&src[i];
  }
  {
    int s = tid >> 2, part = tid & 3;
    const float* src = ws + UAK_OFF + ((size_t)(b * 64 + s)) * 512 + j0 + part * 16;
    float* dst = &sUAK[s][part * 16];
#pragma unroll
    for (int i = 0; i < 16; i += 4) *(float4*)&dst[i] = *(const float4*)&src[i];
  }
  if (tid < 64) { sVa[tid] = Va_w[j0 + tid]; sWab[tid] = Wa_b[j0 + tid]; }
  if (tid < 192) sBhh[tid] = b_hh[(tid >> 6) * 512 + j0 + (tid & 63)];
  const float va_b = Va_b[0];
  __syncthreads();

  for (int t = 0; t < T; ++t) {
    // ---- wait for h_t ----
    if (t > 0) {
      if (tid == 0)
        while (load_coh_i32(&flg[(t - 1) * 64 + b * 2]) != 8) __builtin_amdgcn_s_sleep(1);
    }
    __syncthreads();
    const float* hcur = ws + HALL_OFF + (size_t)t * B * H + b * H;
    sh[tid] = hcur[tid];
    sh[tid + 256] = hcur[tid + 256];
    // prefetch GIE for this step
    float gival = 0.f;
    if (tid < 192)
      gival = GIE[((size_t)b * T + t) * G3 + (tid >> 6) * 512 + j0 + (tid & 63)];
    __syncthreads();
    if (tid < 256) sH2[tid] = pack_h2(sh[2 * tid], sh[2 * tid + 1]);
    __syncthreads();

    // ---- q slice (coalesced k-major): jq = tid&63, kp = tid>>6 ----
    {
      int jq = tid & 63, kp = tid >> 6;
      const unsigned* wp = WA2T + (size_t)(kp * 64) * 512 + j0 + jq;
      float acc = 0.f;
#pragma unroll 8
      for (int kk = 0; kk < 64; kk++)
        acc = dot2acc(wp[(size_t)kk * 512], sH2[kp * 64 + kk], acc);
      qp[jq][kp] = acc;
    }
    __syncthreads();
    if (tid < 64)
      sq[tid] = qp[tid][0] + qp[tid][1] + qp[tid][2] + qp[tid][3] + sWab[tid];
    __syncthreads();
    // ---- score partials over this WG's 64-j slice (f32 LDS) ----
    {
      int s = tid >> 2, jc = tid & 3;
      float accs = 0.f;
#pragma unroll
      for (int i = 0; i < 16; i++) {
        int j = jc * 16 + i;
        accs += sVa[j] * fast_tanh(sq[j] + sUAK[s][j]);
      }
      spp[s][jc] = accs;
    }
    __syncthreads();
    if (tid < 64) {
      float v = spp[tid][0] + spp[tid][1] + spp[tid][2] + spp[tid][3];
      if (cb == 0) v += va_b;
      sps[tid] = v;
    }
    __syncthreads();
    if (tid < 16)
      store_coh_f32x4(SCP + ((size_t)b * 8 + cb) * 64 + tid * 4, *(f32x4*)&sps[tid * 4]);
    if (tid == 0) {
      asm volatile("s_waitcnt vmcnt(0)" ::: "memory");
      __hip_atomic_fetch_add(&flg[t * 64 + b * 2 + 1], 1,
                             __ATOMIC_RELAXED, __HIP_MEMORY_SCOPE_AGENT);
    }

    // ---- gh (coalesced k-major f16): 3 waves ----
    float gh = 0.f;
    if (tid < 192) {
      int gate = tid >> 6, lane = tid & 63;
      const unsigned* wp = WHH2T + gate * 512 + j0 + lane;
      float g0 = 0.f, g1 = 0.f;
#pragma unroll 8
      for (int kk = 0; kk < 256; kk += 2) {
        g0 = dot2acc(wp[(size_t)kk * 1536], sH2[kk], g0);
        g1 = dot2acc(wp[(size_t)(kk + 1) * 1536], sH2[kk + 1], g1);
      }
      gh = g0 + g1 + sBhh[tid];
    }
    // ---- wait all 8 score slices of batch b ----
    if (tid == 0)
      while (load_coh_i32(&flg[t * 64 + b * 2 + 1]) != 8) __builtin_amdgcn_s_sleep(1);
    __syncthreads();
    // ---- coherent SCP read + reduce + softmax ----
    if (tid < 128) {
      f32x4 v = load_coh_f32x4(SCP + (size_t)b * 512 + tid * 4);
      *(f32x4*)&scg[tid >> 4][(tid & 15) * 4] = v;
    }
    __syncthreads();
    if (tid < 64) {
      float v = scg[0][tid] + scg[1][tid] + scg[2][tid] + scg[3][tid]
              + scg[4][tid] + scg[5][tid] + scg[6][tid] + scg[7][tid];
      float m = v;
      for (int o = 32; o; o >>= 1) m = fmaxf(m, __shfl_xor(m, o, 64));
      float e = __expf(v - m);
      float su = e;
      for (int o = 32; o; o >>= 1) su += __shfl_xor(su, o, 64);
      float wt = e / su;
      swt[tid] = wt;
      if (cb == 0) attn_out[((size_t)b * T + t) * S + tid] = wt;
    }
    __syncthreads();
    // ---- gic = KWT . wt (LDS f32) ; combine ----
    if (tid < 192) {
      int gate = tid >> 6, lane = tid & 63;
      float gic = 0.f;
#pragma unroll
      for (int s4 = 0; s4 < 64; s4 += 4) {
        float4 k4 = *(const float4*)&sKWT[tid][s4];
        gic += k4.x * swt[s4] + k4.y * swt[s4 + 1] + k4.z * swt[s4 + 2] + k4.w * swt[s4 + 3];
      }
      float gi = gival + gic;
      if (gate == 0) sga[0][lane] = gi + gh;
      else if (gate == 1) sga[1][lane] = gi + gh;
      else { sga[2][lane] = gi; sga[3][lane] = gh; }
    }
    __syncthreads();
    // ---- GRU update for the 64 owned h-cols ----
    if (tid < 64) {
      float r = fast_sig(sga[0][tid]);
      float z = fast_sig(sga[1][tid]);
      float n = fast_tanh(sga[2][tid] + r * sga[3][tid]);
      float hold = sh[j0 + tid];
      float hn = (1.f - z) * n + z * hold;
      shn[tid] = hn;
      HBF[((size_t)b * T + t) * H + j0 + tid] = __float2bfloat16(hn);
    }
    __syncthreads();
    if (tid < 16)
      store_coh_f32x4(ws + HALL_OFF + (size_t)(t + 1) * B * H + b * H + j0 + tid * 4,
                      *(f32x4*)&shn[tid * 4]);
    if (tid == 0) {
      asm volatile("s_waitcnt vmcnt(0)" ::: "memory");
      __hip_atomic_fetch_add(&flg[t * 64 + b * 2], 1,
                             __ATOMIC_RELAXED, __HIP_MEMORY_SCOPE_AGENT);
    }
  }
}

// -------- bf16 MFMA out-projection w/ global_load_lds + fused softmax stats --------
// [2048,512] x [32000,512]^T; per block also computes per-row (max,sumexp) over its
// 128 cols -> stats[row][bn*2].
__global__ __launch_bounds__(256) void k_outgemm(
    const __hip_bfloat16* __restrict__ Abf, const __hip_bfloat16* __restrict__ Bbf,
    const float* __restrict__ bias, float* __restrict__ Cmat,
    float* __restrict__ stats) {
  __shared__ __align__(16) short As[128 * 32];
  __shared__ __align__(16) short Bs[128 * 32];
  __shared__ float sredM[2][128];
  __shared__ float sredS[2][128];
  int bm = blockIdx.y, bn = blockIdx.x;
  int tid = threadIdx.x;
  int lane = tid & 63, wv = tid >> 6;
  int wm = wv >> 1, wn = wv & 1;
  int kc = lane >> 4, rl = lane & 15;
  f32x4 acc[4][4] = {};
  int c0 = wv * 128 + lane, c1 = c0 + 64;
  const __hip_bfloat16* ga0 = Abf + (size_t)(bm * 128 + (c0 >> 2)) * 512 + (c0 & 3) * 8;
  const __hip_bfloat16* ga1 = Abf + (size_t)(bm * 128 + (c1 >> 2)) * 512 + (c1 & 3) * 8;
  const __hip_bfloat16* gb0 = Bbf + (size_t)(bn * 128 + (c0 >> 2)) * 512 + (c0 & 3) * 8;
  const __hip_bfloat16* gb1 = Bbf + (size_t)(bn * 128 + (c1 >> 2)) * 512 + (c1 & 3) * 8;
  for (int k0 = 0; k0 < 512; k0 += 32) {
    __syncthreads();
    __builtin_amdgcn_global_load_lds(
        (const __attribute__((address_space(1))) void*)(ga0 + k0),
        (__attribute__((address_space(3))) void*)((char*)As + wv * 2048), 16, 0, 0);
    __builtin_amdgcn_global_load_lds(
        (const __attribute__((address_space(1))) void*)(ga1 + k0),
        (__attribute__((address_space(3))) void*)((char*)As + wv * 2048 + 1024), 16, 0, 0);
    __builtin_amdgcn_global_load_lds(
        (const __attribute__((address_space(1))) void*)(gb0 + k0),
        (__attribute__((address_space(3))) void*)((char*)Bs + wv * 2048), 16, 0, 0);
    __builtin_amdgcn_global_load_lds(
        (const __attribute__((address_space(1))) void*)(gb1 + k0),
        (__attribute__((address_space(3))) void*)((char*)Bs + wv * 2048 + 1024), 16, 0, 0);
    __syncthreads();   // barrier drains vmcnt -> LDS tiles complete
    bf16x8 af[4], bfv[4];
#pragma unroll
    for (int f = 0; f < 4; f++) {
      af[f] = *(const bf16x8*)&As[(wm * 64 + f * 16 + rl) * 32 + kc * 8];
      bfv[f] = *(const bf16x8*)&Bs[(wn * 64 + f * 16 + rl) * 32 + kc * 8];
    }
#pragma unroll
    for (int i = 0; i < 4; i++)
#pragma unroll
      for (int j = 0; j < 4; j++)
        acc[i][j] = __builtin_amdgcn_mfma_f32_16x16x32_bf16(af[i], bfv[j], acc[i][j], 0, 0, 0);
  }
  int cl = lane & 15, rg = lane >> 4;
  float bv[4];
#pragma unroll
  for (int j = 0; j < 4; j++) bv[j] = bias[bn * 128 + wn * 64 + j * 16 + cl];
  // pass 1: store C + per-(i,r) max over j
  float vmax[4][4];
#pragma unroll
  for (int i = 0; i < 4; i++) {
    int m = bm * 128 + wm * 64 + i * 16 + rg * 4;
#pragma unroll
    for (int r = 0; r < 4; r++) vmax[i][r] = -1e30f;
#pragma unroll
    for (int j = 0; j < 4; j++) {
      int n = bn * 128 + wn * 64 + j * 16 + cl;
#pragma unroll
      for (int r = 0; r < 4; r++) {
        float val = acc[i][j][r] + bv[j];
        Cmat[(size_t)(m + r) * V + n] = val;
        vmax[i][r] = fmaxf(vmax[i][r], val);
      }
    }
  }
  // reduce max over cl (16-lane groups)
#pragma unroll
  for (int o = 1; o < 16; o <<= 1)
#pragma unroll
    for (int i = 0; i < 4; i++)
#pragma unroll
      for (int r = 0; r < 4; r++)
        vmax[i][r] = fmaxf(vmax[i][r], __shfl_xor(vmax[i][r], o, 64));
  // pass 2: sumexp with row-max
  float vsum[4][4] = {};
#pragma unroll
  for (int i = 0; i < 4; i++)
#pragma unroll
    for (int j = 0; j < 4; j++)
#pragma unroll
      for (int r = 0; r < 4; r++)
        vsum[i][r] += __expf(acc[i][j][r] + bv[j] - vmax[i][r]);
#pragma unroll
  for (int o = 1; o < 16; o <<= 1)
#pragma unroll
    for (int i = 0; i < 4; i++)
#pragma unroll
      for (int r = 0; r < 4; r++)
        vsum[i][r] += __shfl_xor(vsum[i][r], o, 64);
  if (cl == 0) {
#pragma unroll
    for (int i = 0; i < 4; i++)
#pragma unroll
      for (int r = 0; r < 4; r++) {
        int rowl = wm * 64 + i * 16 + rg * 4 + r;
        sredM[wn][rowl] = vmax[i][r];
        sredS[wn][rowl] = vsum[i][r];
      }
  }
  __syncthreads();
  if (tid < 128) {
    float m0 = sredM[0][tid], m1 = sredM[1][tid];
    float M = fmaxf(m0, m1);
    float Sv = sredS[0][tid] * __expf(m0 - M) + sredS[1][tid] * __expf(m1 - M);
    float* st = stats + (size_t)(bm * 128 + tid) * 512 + bn * 2;
    st[0] = M; st[1] = Sv;
  }
}

// -------------------- final pass: lse from stats, subtract in-place --------------------
__global__ __launch_bounds__(256) void k_lsm_final(float* __restrict__ Cmat,
                                                   const float* __restrict__ stats) {
  int row = blockIdx.x;
  int tid = threadIdx.x;
  __shared__ float sM[4], sS[4];
  float m = -1e30f, s = 0.f;
  if (tid < 250) {
    float2 v = *(const float2*)&stats[(size_t)row * 512 + tid * 2];
    m = v.x; s = v.y;
  }
  for (int o = 32; o; o >>= 1) {
    float om = __shfl_xor(m, o, 64), os = __shfl_xor(s, o, 64);
    float nm = fmaxf(m, om);
    s = s * __expf(m - nm) + os * __expf(om - nm);
    m = nm;
  }
  if ((tid & 63) == 0) { sM[tid >> 6] = m; sS[tid >> 6] = s; }
  __syncthreads();
  float M = fmaxf(fmaxf(sM[0], sM[1]), fmaxf(sM[2], sM[3]));
  float Ssum = sS[0] * __expf(sM[0] - M) + sS[1] * __expf(sM[1] - M)
             + sS[2] * __expf(sM[2] - M) + sS[3] * __expf(sM[3] - M);
  float lse = M + __logf(Ssum);
  float* p = Cmat + (size_t)row * V;
  for (int i = tid * 4; i < V; i += 1024) {
    float4 v = *(const float4*)&p[i];
    v.x -= lse; v.y -= lse; v.z -= lse; v.w -= lse;
    *(float4*)&p[i] = v;
  }
}

__global__ void k_copy_ht(const float* __restrict__ hsrc, float* __restrict__ o) {
  int i = blockIdx.x * 256 + threadIdx.x;
  if (i < B * H) o[i] = hsrc[i];
}

extern "C" void kernel_launch(void* const* d_in, const int* in_sizes, int n_in,
                              void* d_out, int out_size, void* d_ws, size_t ws_size,
                              hipStream_t stream) {
  (void)in_sizes; (void)n_in; (void)out_size; (void)ws_size;
  const float* keys = (const float*)d_in[0];
  const float* ehid = (const float*)d_in[1];
  const int* tgt    = (const int*)d_in[2];
  const float* emb  = (const float*)d_in[4];
  const float* Wa_w = (const float*)d_in[5];
  const float* Wa_b = (const float*)d_in[6];
  const float* Ua_w = (const float*)d_in[7];
  const float* Ua_b = (const float*)d_in[8];
  const float* Va_w = (const float*)d_in[9];
  const float* Va_b = (const float*)d_in[10];
  const float* W_ih = (const float*)d_in[11];
  const float* W_hh = (const float*)d_in[12];
  const float* b_ih = (const float*)d_in[13];
  const float* b_hh = (const float*)d_in[14];
  const float* out_w = (const float*)d_in[15];
  const float* out_b = (const float*)d_in[16];
  float* ws = (float*)d_ws;
  float* out = (float*)d_out;
  float* logits = out;                              // [B,T,V]
  float* ht_out = out + (size_t)B * T * V;          // [1,B,H]
  float* attn_out = ht_out + (size_t)B * H;         // [B,T,S]

  hipLaunchKernelGGL(k_init, dim3(64), dim3(256), 0, stream, ehid, tgt, ws);
  // Ua_keys = keys @ Ua_w.T + Ua_b -> [B*S][512]
  hipLaunchKernelGGL(k_gemm_at, dim3(32, 8), dim3(256), 0, stream,
                     keys, Ua_w, 512, Ua_b, ws + UAK_OFF, (const int*)nullptr, 512);
  // Gi_e = emb[tokens] @ W_ih[:, :512].T + b_ih -> [B*T][1536]
  hipLaunchKernelGGL(k_gemm_at, dim3(32, 24), dim3(256), 0, stream,
                     emb, W_ih, 1024, b_ih, ws + GIE_OFF, (const int*)(ws + ROWIDX_OFF), G3);
  // KWT f32 [b][col][s]
  hipLaunchKernelGGL(k_gemm_kwt, dim3(24, 32), dim3(256), 0, stream,
                     W_ih, keys, ws + KWT_OFF);
  // k-major packed f16x2 weights
  hipLaunchKernelGGL(k_pack_t, dim3(512), dim3(256), 0, stream,
                     Wa_w, (unsigned*)(ws + WA2T_OFF), 512);
  hipLaunchKernelGGL(k_pack_t, dim3(1536), dim3(256), 0, stream,
                     W_hh, (unsigned*)(ws + WHH2T_OFF), 1536);
  // persistent recurrence (r9 structure)
  hipLaunchKernelGGL(k_recur, dim3(256), dim3(256), 0, stream,
                     Wa_b, Va_w, Va_b, b_hh,
                     (const unsigned*)(ws + WA2T_OFF), (const unsigned*)(ws + WHH2T_OFF),
                     ws, attn_out);
  hipLaunchKernelGGL(k_copy_ht, dim3(64), dim3(256), 0, stream,
                     ws + HALL_OFF + (size_t)T * B * H, ht_out);
  // bf16 out_w copy into the (now dead) precompute region
  hipLaunchKernelGGL(k_conv_outw, dim3((V * H / 4 + 255) / 256), dim3(256), 0, stream,
                     out_w, (ushort*)(ws + OWBF_OFF), V * H / 4);
  // out-GEMM with fused per-block softmax stats (stats reuse dead HALL region)
  hipLaunchKernelGGL(k_outgemm, dim3(250, 16), dim3(256), 0, stream,
                     (const __hip_bfloat16*)(ws + HBF_OFF),
                     (const __hip_bfloat16*)(ws + OWBF_OFF), out_b, logits,
                     ws + STATS_OFF);
  hipLaunchKernelGGL(k_lsm_final, dim3(BT), dim3(256), 0, stream,
                     logits, ws + STATS_OFF);
}

// Round 12
// 1012.859 us; speedup vs baseline: 1.5287x; 1.4039x over previous
//
#include <hip/hip_runtime.h>
#include <hip/hip_bf16.h>
#include <hip/hip_fp16.h>
#include <math.h>

constexpr int B = 32, S = 64, T = 64, H = 512, V = 32000;
constexpr int G3 = 3 * H;     // 1536
constexpr int BT = B * T;     // 2048

// ---- workspace layout (float slots) ----
constexpr size_t UAK_OFF    = 0;          // f32 [B*S][512]      1,048,576
constexpr size_t GIE_OFF    = 1048576;    // f32 [B*T][1536]     -> 4,194,304
constexpr size_t KWTH_OFF   = 4194304;    // f16 [B][G3][64]     1,572,864 -> 5,767,168
constexpr size_t WA2T_OFF   = 5767168;    // u32 [256][512]        131,072 -> 5,898,240
constexpr size_t WHH2T_OFF  = 5898240;    // u32 [256][1536]       393,216 -> 6,291,456
constexpr size_t ROWIDX_OFF = 6291456;    // 2048 ints             -> 6,293,504
constexpr size_t SCPT_OFF   = 6293504;    // f32 [T][B][8][64]   1,048,576 -> 7,342,080
constexpr size_t FLG_OFF    = 7342080;    // T*64 ints             -> 7,346,176
constexpr size_t OWBF_OFF   = 0;          // bf16 [V*H] = 8,192,000 slots; aliases all
                                          // of the above (dead after k_recur)
constexpr size_t HALL_OFF   = 8192000;    // f32 [(T+1)*B*H]     1,064,960 -> 9,256,960
constexpr size_t STATS_OFF  = 8192000;    // f32 [2048][512]; reuses HALL (dead after copy_ht)
constexpr size_t HBF_OFF    = 9256960;    // bf16 [B*T*H] 524,288 slots -> 9,781,248
// f16 staging for precompute MFMA (dead after precompute; ws >= 14.0M slots proven in r1)
constexpr size_t KEYSH_OFF  = 10000000;   // f16 [2048][512] 524,288 -> 10,524,288
constexpr size_t GEH_OFF    = 10524288;   // f16 [2048][512] -> 11,048,576
constexpr size_t UAWH_OFF   = 11048576;   // f16 [512][512]  -> 11,179,648
constexpr size_t WLOH_OFF   = 11179648;   // f16 [1536][512] -> 11,572,864
constexpr size_t WCTXH_OFF  = 11572864;   // f16 [1536][512] -> 11,966,080

typedef __attribute__((ext_vector_type(8))) short bf16x8;
typedef __attribute__((ext_vector_type(4))) float f32x4;
typedef _Float16 f16x8 __attribute__((ext_vector_type(8)));
typedef _Float16 h2v __attribute__((ext_vector_type(2)));

__device__ __forceinline__ float fast_tanh(float x) {
  float ax = fabsf(x);
  float e = __expf(-2.f * ax);
  float r = (1.f - e) / (1.f + e);
  return x < 0.f ? -r : r;
}
__device__ __forceinline__ float fast_sig(float x) {
  return 1.f / (1.f + __expf(-x));
}
__device__ __forceinline__ unsigned pack_h2(float a, float b) {
  __half2 h = __floats2half2_rn(a, b);
  return *(unsigned*)&h;
}
__device__ __forceinline__ ushort f2h(float v) {
  __half h = __float2half(v);
  return *(ushort*)&h;
}
__device__ __forceinline__ void unp2(unsigned v, float* d) {
  __half2 h = *(__half2*)&v;
  d[0] = __low2float(h); d[1] = __high2float(h);
}
__device__ __forceinline__ float dot2acc(unsigned w, unsigned h, float c) {
  return __builtin_amdgcn_fdot2(__builtin_bit_cast(h2v, w),
                                __builtin_bit_cast(h2v, h), c, false);
}
__device__ __forceinline__ int load_coh_i32(const int* p) {
  int v;
  asm volatile("global_load_dword %0, %1, off sc0 sc1\n\ts_waitcnt vmcnt(0)"
               : "=v"(v) : "v"(p) : "memory");
  return v;
}
__device__ __forceinline__ void store_coh_f32x4(float* p, f32x4 v) {
  asm volatile("global_store_dwordx4 %0, %1, off sc0 sc1" :: "v"(p), "v"(v) : "memory");
}

// -------------------- init: h0, token row indices, flags --------------------
__global__ void k_init(const float* __restrict__ eh, const int* __restrict__ tgt,
                       float* __restrict__ ws) {
  int i = blockIdx.x * 256 + threadIdx.x;      // grid 64*256 = 16384
  if (i < B * H) ws[HALL_OFF + i] = eh[i];
  if (i < BT) {
    int b = i / T, t = i % T;
    ((int*)(ws + ROWIDX_OFF))[i] = (t == 0) ? 0 : tgt[b * T + t - 1];
  }
  if (i < T * 64) ((int*)(ws + FLG_OFF))[i] = 0;
}

// -------------------- f32 rows -> f16 rows (optional gather) --------------------
__global__ void k_conv_f16(const float* __restrict__ in, int ld, int coloff,
                           const int* __restrict__ rowidx, ushort* __restrict__ out,
                           int rows) {
  int i4 = (blockIdx.x * 256 + threadIdx.x) * 4;
  if (i4 < rows * 512) {
    int row = i4 >> 9, k = i4 & 511;
    int ar = rowidx ? rowidx[row] : row;
    float4 v = *(const float4*)&in[(size_t)ar * ld + coloff + k];
    ushort4 o;
    o.x = f2h(v.x); o.y = f2h(v.y); o.z = f2h(v.z); o.w = f2h(v.w);
    *(ushort4*)&out[i4] = o;
  }
}

// -------------------- f32 [R][512] -> k-major packed f16x2 [256][R] --------------------
__global__ void k_pack_t(const float* __restrict__ in, unsigned* __restrict__ out, int R) {
  int i = blockIdx.x * 256 + threadIdx.x;
  if (i < R * 256) {
    int r = i >> 8, kk = i & 255;
    float2 v = *(const float2*)&in[(size_t)r * 512 + 2 * kk];
    out[(size_t)kk * R + r] = pack_h2(v.x, v.y);
  }
}

// -------------------- out_w fp32 -> bf16 (runs AFTER recurrence; aliases ws) ----
__global__ void k_conv_outw(const float* __restrict__ w, ushort* __restrict__ o, int n4) {
  int i = blockIdx.x * blockDim.x + threadIdx.x;
  if (i < n4) {
    float4 v = *(const float4*)&w[(size_t)i * 4];
    ushort4 u;
    __hip_bfloat16 h0 = __float2bfloat16(v.x); u.x = *(ushort*)&h0;
    __hip_bfloat16 h1 = __float2bfloat16(v.y); u.y = *(ushort*)&h1;
    __hip_bfloat16 h2 = __float2bfloat16(v.z); u.z = *(ushort*)&h2;
    __hip_bfloat16 h3 = __float2bfloat16(v.w); u.w = *(ushort*)&h3;
    *(ushort4*)&o[(size_t)i * 4] = u;
  }
}

// -------- f16 MFMA GEMM 128x128 tiles: C[m*ldc+n] = Ah[m,:].Bh[n,:] + bias[n] --------
__global__ __launch_bounds__(256) void k_mfma128(
    const ushort* __restrict__ Ah, const ushort* __restrict__ Bh,
    const float* __restrict__ bias, float* __restrict__ C, int ldc) {
  __shared__ __align__(16) ushort As[128 * 32];
  __shared__ __align__(16) ushort Bs[128 * 32];
  int bm = blockIdx.y, bn = blockIdx.x;
  int tid = threadIdx.x;
  int lane = tid & 63, wv = tid >> 6;
  int wm = wv >> 1, wn = wv & 1;
  int kc = lane >> 4, rl = lane & 15;
  f32x4 acc[4][4] = {};
  int c0 = wv * 128 + lane, c1 = c0 + 64;
  const ushort* ga0 = Ah + (size_t)(bm * 128 + (c0 >> 2)) * 512 + (c0 & 3) * 8;
  const ushort* ga1 = Ah + (size_t)(bm * 128 + (c1 >> 2)) * 512 + (c1 & 3) * 8;
  const ushort* gb0 = Bh + (size_t)(bn * 128 + (c0 >> 2)) * 512 + (c0 & 3) * 8;
  const ushort* gb1 = Bh + (size_t)(bn * 128 + (c1 >> 2)) * 512 + (c1 & 3) * 8;
  for (int k0 = 0; k0 < 512; k0 += 32) {
    __syncthreads();
    __builtin_amdgcn_global_load_lds(
        (const __attribute__((address_space(1))) void*)(ga0 + k0),
        (__attribute__((address_space(3))) void*)((char*)As + wv * 2048), 16, 0, 0);
    __builtin_amdgcn_global_load_lds(
        (const __attribute__((address_space(1))) void*)(ga1 + k0),
        (__attribute__((address_space(3))) void*)((char*)As + wv * 2048 + 1024), 16, 0, 0);
    __builtin_amdgcn_global_load_lds(
        (const __attribute__((address_space(1))) void*)(gb0 + k0),
        (__attribute__((address_space(3))) void*)((char*)Bs + wv * 2048), 16, 0, 0);
    __builtin_amdgcn_global_load_lds(
        (const __attribute__((address_space(1))) void*)(gb1 + k0),
        (__attribute__((address_space(3))) void*)((char*)Bs + wv * 2048 + 1024), 16, 0, 0);
    __syncthreads();
    f16x8 af[4], bfv[4];
#pragma unroll
    for (int f = 0; f < 4; f++) {
      af[f] = *(const f16x8*)&As[(wm * 64 + f * 16 + rl) * 32 + kc * 8];
      bfv[f] = *(const f16x8*)&Bs[(wn * 64 + f * 16 + rl) * 32 + kc * 8];
    }
#pragma unroll
    for (int i = 0; i < 4; i++)
#pragma unroll
      for (int j = 0; j < 4; j++)
        acc[i][j] = __builtin_amdgcn_mfma_f32_16x16x32_f16(af[i], bfv[j], acc[i][j], 0, 0, 0);
  }
  int cl = lane & 15, rg = lane >> 4;
#pragma unroll
  for (int i = 0; i < 4; i++) {
    int m = bm * 128 + wm * 64 + i * 16 + rg * 4;
#pragma unroll
    for (int j = 0; j < 4; j++) {
      int n = bn * 128 + wn * 64 + j * 16 + cl;
      float bv = bias[n];
#pragma unroll
      for (int r = 0; r < 4; r++)
        C[(size_t)(m + r) * ldc + n] = acc[i][j][r] + bv;
    }
  }
}

// -------- f16 MFMA KWT: per b, [1536 x 64] = Wctx[1536,512] . keys_b[64,512]^T -> f16 out ----
__global__ __launch_bounds__(256) void k_mfma_kwt(
    const ushort* __restrict__ Wctxh, const ushort* __restrict__ keysh,
    ushort* __restrict__ KWTh) {
  __shared__ __align__(16) ushort As[128 * 32];
  __shared__ __align__(16) ushort Bs[64 * 32];
  int bm = blockIdx.x, b = blockIdx.y;
  int tid = threadIdx.x;
  int lane = tid & 63, wv = tid >> 6;
  int kc = lane >> 4, rl = lane & 15;
  f32x4 acc[2][4] = {};
  int c0 = tid, c2 = tid + 256;
  const ushort* ga0 = Wctxh + (size_t)(bm * 128 + (c0 >> 2)) * 512 + (c0 & 3) * 8;
  const ushort* ga1 = Wctxh + (size_t)(bm * 128 + (c2 >> 2)) * 512 + (c2 & 3) * 8;
  const ushort* gb0 = keysh + (size_t)(b * 64 + (c0 >> 2)) * 512 + (c0 & 3) * 8;
  for (int k0 = 0; k0 < 512; k0 += 32) {
    __syncthreads();
    __builtin_amdgcn_global_load_lds(
        (const __attribute__((address_space(1))) void*)(ga0 + k0),
        (__attribute__((address_space(3))) void*)((char*)As + wv * 1024), 16, 0, 0);
    __builtin_amdgcn_global_load_lds(
        (const __attribute__((address_space(1))) void*)(ga1 + k0),
        (__attribute__((address_space(3))) void*)((char*)As + 4096 + wv * 1024), 16, 0, 0);
    __builtin_amdgcn_global_load_lds(
        (const __attribute__((address_space(1))) void*)(gb0 + k0),
        (__attribute__((address_space(3))) void*)((char*)Bs + wv * 1024), 16, 0, 0);
    __syncthreads();
    f16x8 af[2], bfv[4];
#pragma unroll
    for (int f = 0; f < 2; f++)
      af[f] = *(const f16x8*)&As[(wv * 32 + f * 16 + rl) * 32 + kc * 8];
#pragma unroll
    for (int j = 0; j < 4; j++)
      bfv[j] = *(const f16x8*)&Bs[(j * 16 + rl) * 32 + kc * 8];
#pragma unroll
    for (int i = 0; i < 2; i++)
#pragma unroll
      for (int j = 0; j < 4; j++)
        acc[i][j] = __builtin_amdgcn_mfma_f32_16x16x32_f16(af[i], bfv[j], acc[i][j], 0, 0, 0);
  }
  int cl = lane & 15, rg = lane >> 4;
#pragma unroll
  for (int i = 0; i < 2; i++) {
    int m = bm * 128 + wv * 32 + i * 16 + rg * 4;
#pragma unroll
    for (int j = 0; j < 4; j++) {
      int n = j * 16 + cl;
#pragma unroll
      for (int r = 0; r < 4; r++)
        KWTh[((size_t)b * G3 + m + r) * 64 + n] = f2h(acc[i][j][r]);
    }
  }
}

// -------------------- persistent recurrence (r9 structure, XCD-co-located) --------------------
// WG w: b = w&31, cb = w>>5  ->  all 8 WGs of batch b share w%8 = b%8 (same XCD under
// round-robin dispatch; perf-only assumption). SCP fully t-rotating -> consumers use
// plain first-touch loads (fresh from shared L2 when co-located, from LLC otherwise).
__global__ __launch_bounds__(256) void k_recur(
    const float* __restrict__ Wa_b, const float* __restrict__ Va_w,
    const float* __restrict__ Va_b, const float* __restrict__ b_hh,
    const unsigned* __restrict__ WA2T, const unsigned* __restrict__ WHH2T,
    float* __restrict__ ws, float* __restrict__ attn_out) {
  const int w = blockIdx.x;
  const int tid = threadIdx.x;
  const int b = w & 31, cb = w >> 5;
  const int j0 = cb * 64;
  int* flg = (int*)(ws + FLG_OFF);
  __hip_bfloat16* HBF = (__hip_bfloat16*)(ws + HBF_OFF);
  const float* GIE = ws + GIE_OFF;
  float* SCPT = ws + SCPT_OFF;
  const ushort* KWTh = (const ushort*)(ws + KWTH_OFF);

  __shared__ float sKWT[192][68];   // 52.2 KB
  __shared__ float sUAK[64][68];    // 17.4 KB
  __shared__ float sh[512];
  __shared__ unsigned sH2[256];
  __shared__ float sq[64];
  __shared__ float qp[64][5];
  __shared__ float spp[64][5];
  __shared__ float sps[64];
  __shared__ float scg[8][64];
  __shared__ float swt[64];
  __shared__ float sga[4][64];
  __shared__ float shn[64];
  __shared__ float sVa[64], sWab[64], sBhh[192];

  // ---- one-time staging ----
#pragma unroll
  for (int g = 0; g < 3; g++) {
    int jl = tid >> 2, part = tid & 3;
    const ushort* src = KWTh + ((size_t)b * G3 + g * 512 + j0 + jl) * 64 + part * 16;
    float* dst = &sKWT[g * 64 + jl][part * 16];
    uint4 u0 = *(const uint4*)src;
    uint4 u1 = *(const uint4*)(src + 8);
    unp2(u0.x, dst); unp2(u0.y, dst + 2); unp2(u0.z, dst + 4); unp2(u0.w, dst + 6);
    unp2(u1.x, dst + 8); unp2(u1.y, dst + 10); unp2(u1.z, dst + 12); unp2(u1.w, dst + 14);
  }
  {
    int s = tid >> 2, part = tid & 3;
    const float* src = ws + UAK_OFF + ((size_t)(b * 64 + s)) * 512 + j0 + part * 16;
    float* dst = &sUAK[s][part * 16];
#pragma unroll
    for (int i = 0; i < 16; i += 4) *(float4*)&dst[i] = *(const float4*)&src[i];
  }
  if (tid < 64) { sVa[tid] = Va_w[j0 + tid]; sWab[tid] = Wa_b[j0 + tid]; }
  if (tid < 192) sBhh[tid] = b_hh[(tid >> 6) * 512 + j0 + (tid & 63)];
  const float va_b = Va_b[0];
  __syncthreads();

  for (int t = 0; t < T; ++t) {
    // ---- wait for h_t ----
    if (t > 0) {
      if (tid == 0)
        while (load_coh_i32(&flg[(t - 1) * 64 + b * 2]) != 8) __builtin_amdgcn_s_sleep(1);
    }
    __syncthreads();
    const float* hcur = ws + HALL_OFF + (size_t)t * B * H + b * H;
    sh[tid] = hcur[tid];
    sh[tid + 256] = hcur[tid + 256];
    // prefetch GIE for this step
    float gival = 0.f;
    if (tid < 192)
      gival = GIE[((size_t)b * T + t) * G3 + (tid >> 6) * 512 + j0 + (tid & 63)];
    __syncthreads();
    if (tid < 256) sH2[tid] = pack_h2(sh[2 * tid], sh[2 * tid + 1]);
    __syncthreads();

    // ---- q slice (coalesced k-major) ----
    {
      int jq = tid & 63, kp = tid >> 6;
      const unsigned* wp = WA2T + (size_t)(kp * 64) * 512 + j0 + jq;
      float acc = 0.f;
#pragma unroll 8
      for (int kk = 0; kk < 64; kk++)
        acc = dot2acc(wp[(size_t)kk * 512], sH2[kp * 64 + kk], acc);
      qp[jq][kp] = acc;
    }
    __syncthreads();
    if (tid < 64)
      sq[tid] = qp[tid][0] + qp[tid][1] + qp[tid][2] + qp[tid][3] + sWab[tid];
    __syncthreads();
    // ---- score partials over this WG's 64-j slice ----
    {
      int s = tid >> 2, jc = tid & 3;
      float accs = 0.f;
#pragma unroll
      for (int i = 0; i < 16; i++) {
        int j = jc * 16 + i;
        accs += sVa[j] * fast_tanh(sq[j] + sUAK[s][j]);
      }
      spp[s][jc] = accs;
    }
    __syncthreads();
    if (tid < 64) {
      float v = spp[tid][0] + spp[tid][1] + spp[tid][2] + spp[tid][3];
      if (cb == 0) v += va_b;
      sps[tid] = v;
    }
    __syncthreads();
    if (tid < 16)
      store_coh_f32x4(SCPT + (((size_t)t * B + b) * 8 + cb) * 64 + tid * 4,
                      *(f32x4*)&sps[tid * 4]);
    if (tid == 0) {
      asm volatile("s_waitcnt vmcnt(0)" ::: "memory");
      __hip_atomic_fetch_add(&flg[t * 64 + b * 2 + 1], 1,
                             __ATOMIC_RELAXED, __HIP_MEMORY_SCOPE_AGENT);
    }

    // ---- gh (coalesced k-major f16): 3 waves ----
    float gh = 0.f;
    if (tid < 192) {
      int gate = tid >> 6, lane = tid & 63;
      const unsigned* wp = WHH2T + gate * 512 + j0 + lane;
      float g0 = 0.f, g1 = 0.f;
#pragma unroll 8
      for (int kk = 0; kk < 256; kk += 2) {
        g0 = dot2acc(wp[(size_t)kk * 1536], sH2[kk], g0);
        g1 = dot2acc(wp[(size_t)(kk + 1) * 1536], sH2[kk + 1], g1);
      }
      gh = g0 + g1 + sBhh[tid];
    }
    // ---- wait all 8 score slices of batch b ----
    if (tid == 0)
      while (load_coh_i32(&flg[t * 64 + b * 2 + 1]) != 8) __builtin_amdgcn_s_sleep(1);
    __syncthreads();
    // ---- SCP read (plain, first-touch rotating) + reduce + softmax ----
    if (tid < 128) {
      f32x4 v = *(const f32x4*)&SCPT[((size_t)t * B + b) * 512 + tid * 4];
      *(f32x4*)&scg[tid >> 4][(tid & 15) * 4] = v;
    }
    __syncthreads();
    if (tid < 64) {
      float v = scg[0][tid] + scg[1][tid] + scg[2][tid] + scg[3][tid]
              + scg[4][tid] + scg[5][tid] + scg[6][tid] + scg[7][tid];
      float m = v;
      for (int o = 32; o; o >>= 1) m = fmaxf(m, __shfl_xor(m, o, 64));
      float e = __expf(v - m);
      float su = e;
      for (int o = 32; o; o >>= 1) su += __shfl_xor(su, o, 64);
      float wt = e / su;
      swt[tid] = wt;
      if (cb == 0) attn_out[((size_t)b * T + t) * S + tid] = wt;
    }
    __syncthreads();
    // ---- gic = KWT . wt (LDS f32) ; combine ----
    if (tid < 192) {
      int gate = tid >> 6, lane = tid & 63;
      float gic = 0.f;
#pragma unroll
      for (int s4 = 0; s4 < 64; s4 += 4) {
        float4 k4 = *(const float4*)&sKWT[tid][s4];
        gic += k4.x * swt[s4] + k4.y * swt[s4 + 1] + k4.z * swt[s4 + 2] + k4.w * swt[s4 + 3];
      }
      float gi = gival + gic;
      if (gate == 0) sga[0][lane] = gi + gh;
      else if (gate == 1) sga[1][lane] = gi + gh;
      else { sga[2][lane] = gi; sga[3][lane] = gh; }
    }
    __syncthreads();
    // ---- GRU update for the 64 owned h-cols ----
    if (tid < 64) {
      float r = fast_sig(sga[0][tid]);
      float z = fast_sig(sga[1][tid]);
      float n = fast_tanh(sga[2][tid] + r * sga[3][tid]);
      float hold = sh[j0 + tid];
      float hn = (1.f - z) * n + z * hold;
      shn[tid] = hn;
      HBF[((size_t)b * T + t) * H + j0 + tid] = __float2bfloat16(hn);
    }
    __syncthreads();
    if (tid < 16)
      store_coh_f32x4(ws + HALL_OFF + (size_t)(t + 1) * B * H + b * H + j0 + tid * 4,
                      *(f32x4*)&shn[tid * 4]);
    if (tid == 0) {
      asm volatile("s_waitcnt vmcnt(0)" ::: "memory");
      __hip_atomic_fetch_add(&flg[t * 64 + b * 2], 1,
                             __ATOMIC_RELAXED, __HIP_MEMORY_SCOPE_AGENT);
    }
  }
}

// -------- bf16 MFMA out-projection w/ global_load_lds + fused softmax stats --------
__global__ __launch_bounds__(256) void k_outgemm(
    const __hip_bfloat16* __restrict__ Abf, const __hip_bfloat16* __restrict__ Bbf,
    const float* __restrict__ bias, float* __restrict__ Cmat,
    float* __restrict__ stats) {
  __shared__ __align__(16) short As[128 * 32];
  __shared__ __align__(16) short Bs[128 * 32];
  __shared__ float sredM[2][128];
  __shared__ float sredS[2][128];
  int bm = blockIdx.y, bn = blockIdx.x;
  int tid = threadIdx.x;
  int lane = tid & 63, wv = tid >> 6;
  int wm = wv >> 1, wn = wv & 1;
  int kc = lane >> 4, rl = lane & 15;
  f32x4 acc[4][4] = {};
  int c0 = wv * 128 + lane, c1 = c0 + 64;
  const __hip_bfloat16* ga0 = Abf + (size_t)(bm * 128 + (c0 >> 2)) * 512 + (c0 & 3) * 8;
  const __hip_bfloat16* ga1 = Abf + (size_t)(bm * 128 + (c1 >> 2)) * 512 + (c1 & 3) * 8;
  const __hip_bfloat16* gb0 = Bbf + (size_t)(bn * 128 + (c0 >> 2)) * 512 + (c0 & 3) * 8;
  const __hip_bfloat16* gb1 = Bbf + (size_t)(bn * 128 + (c1 >> 2)) * 512 + (c1 & 3) * 8;
  for (int k0 = 0; k0 < 512; k0 += 32) {
    __syncthreads();
    __builtin_amdgcn_global_load_lds(
        (const __attribute__((address_space(1))) void*)(ga0 + k0),
        (__attribute__((address_space(3))) void*)((char*)As + wv * 2048), 16, 0, 0);
    __builtin_amdgcn_global_load_lds(
        (const __attribute__((address_space(1))) void*)(ga1 + k0),
        (__attribute__((address_space(3))) void*)((char*)As + wv * 2048 + 1024), 16, 0, 0);
    __builtin_amdgcn_global_load_lds(
        (const __attribute__((address_space(1))) void*)(gb0 + k0),
        (__attribute__((address_space(3))) void*)((char*)Bs + wv * 2048), 16, 0, 0);
    __builtin_amdgcn_global_load_lds(
        (const __attribute__((address_space(1))) void*)(gb1 + k0),
        (__attribute__((address_space(3))) void*)((char*)Bs + wv * 2048 + 1024), 16, 0, 0);
    __syncthreads();
    bf16x8 af[4], bfv[4];
#pragma unroll
    for (int f = 0; f < 4; f++) {
      af[f] = *(const bf16x8*)&As[(wm * 64 + f * 16 + rl) * 32 + kc * 8];
      bfv[f] = *(const bf16x8*)&Bs[(wn * 64 + f * 16 + rl) * 32 + kc * 8];
    }
#pragma unroll
    for (int i = 0; i < 4; i++)
#pragma unroll
      for (int j = 0; j < 4; j++)
        acc[i][j] = __builtin_amdgcn_mfma_f32_16x16x32_bf16(af[i], bfv[j], acc[i][j], 0, 0, 0);
  }
  int cl = lane & 15, rg = lane >> 4;
  float bv[4];
#pragma unroll
  for (int j = 0; j < 4; j++) bv[j] = bias[bn * 128 + wn * 64 + j * 16 + cl];
  float vmax[4][4];
#pragma unroll
  for (int i = 0; i < 4; i++) {
    int m = bm * 128 + wm * 64 + i * 16 + rg * 4;
#pragma unroll
    for (int r = 0; r < 4; r++) vmax[i][r] = -1e30f;
#pragma unroll
    for (int j = 0; j < 4; j++) {
      int n = bn * 128 + wn * 64 + j * 16 + cl;
#pragma unroll
      for (int r = 0; r < 4; r++) {
        float val = acc[i][j][r] + bv[j];
        Cmat[(size_t)(m + r) * V + n] = val;
        vmax[i][r] = fmaxf(vmax[i][r], val);
      }
    }
  }
#pragma unroll
  for (int o = 1; o < 16; o <<= 1)
#pragma unroll
    for (int i = 0; i < 4; i++)
#pragma unroll
      for (int r = 0; r < 4; r++)
        vmax[i][r] = fmaxf(vmax[i][r], __shfl_xor(vmax[i][r], o, 64));
  float vsum[4][4] = {};
#pragma unroll
  for (int i = 0; i < 4; i++)
#pragma unroll
    for (int j = 0; j < 4; j++)
#pragma unroll
      for (int r = 0; r < 4; r++)
        vsum[i][r] += __expf(acc[i][j][r] + bv[j] - vmax[i][r]);
#pragma unroll
  for (int o = 1; o < 16; o <<= 1)
#pragma unroll
    for (int i = 0; i < 4; i++)
#pragma unroll
      for (int r = 0; r < 4; r++)
        vsum[i][r] += __shfl_xor(vsum[i][r], o, 64);
  if (cl == 0) {
#pragma unroll
    for (int i = 0; i < 4; i++)
#pragma unroll
      for (int r = 0; r < 4; r++) {
        int rowl = wm * 64 + i * 16 + rg * 4 + r;
        sredM[wn][rowl] = vmax[i][r];
        sredS[wn][rowl] = vsum[i][r];
      }
  }
  __syncthreads();
  if (tid < 128) {
    float m0 = sredM[0][tid], m1 = sredM[1][tid];
    float M = fmaxf(m0, m1);
    float Sv = sredS[0][tid] * __expf(m0 - M) + sredS[1][tid] * __expf(m1 - M);
    float* st = stats + (size_t)(bm * 128 + tid) * 512 + bn * 2;
    st[0] = M; st[1] = Sv;
  }
}

// -------------------- final pass: lse from stats, subtract in-place --------------------
__global__ __launch_bounds__(256) void k_lsm_final(float* __restrict__ Cmat,
                                                   const float* __restrict__ stats) {
  int row = blockIdx.x;
  int tid = threadIdx.x;
  __shared__ float sM[4], sS[4];
  float m = -1e30f, s = 0.f;
  if (tid < 250) {
    float2 v = *(const float2*)&stats[(size_t)row * 512 + tid * 2];
    m = v.x; s = v.y;
  }
  for (int o = 32; o; o >>= 1) {
    float om = __shfl_xor(m, o, 64), os = __shfl_xor(s, o, 64);
    float nm = fmaxf(m, om);
    s = s * __expf(m - nm) + os * __expf(om - nm);
    m = nm;
  }
  if ((tid & 63) == 0) { sM[tid >> 6] = m; sS[tid >> 6] = s; }
  __syncthreads();
  float M = fmaxf(fmaxf(sM[0], sM[1]), fmaxf(sM[2], sM[3]));
  float Ssum = sS[0] * __expf(sM[0] - M) + sS[1] * __expf(sM[1] - M)
             + sS[2] * __expf(sM[2] - M) + sS[3] * __expf(sM[3] - M);
  float lse = M + __logf(Ssum);
  float* p = Cmat + (size_t)row * V;
  for (int i = tid * 4; i < V; i += 1024) {
    float4 v = *(const float4*)&p[i];
    v.x -= lse; v.y -= lse; v.z -= lse; v.w -= lse;
    *(float4*)&p[i] = v;
  }
}

__global__ void k_copy_ht(const float* __restrict__ hsrc, float* __restrict__ o) {
  int i = blockIdx.x * 256 + threadIdx.x;
  if (i < B * H) o[i] = hsrc[i];
}

extern "C" void kernel_launch(void* const* d_in, const int* in_sizes, int n_in,
                              void* d_out, int out_size, void* d_ws, size_t ws_size,
                              hipStream_t stream) {
  (void)in_sizes; (void)n_in; (void)out_size; (void)ws_size;
  const float* keys = (const float*)d_in[0];
  const float* ehid = (const float*)d_in[1];
  const int* tgt    = (const int*)d_in[2];
  const float* emb  = (const float*)d_in[4];
  const float* Wa_w = (const float*)d_in[5];
  const float* Wa_b = (const float*)d_in[6];
  const float* Ua_w = (const float*)d_in[7];
  const float* Ua_b = (const float*)d_in[8];
  const float* Va_w = (const float*)d_in[9];
  const float* Va_b = (const float*)d_in[10];
  const float* W_ih = (const float*)d_in[11];
  const float* W_hh = (const float*)d_in[12];
  const float* b_ih = (const float*)d_in[13];
  const float* b_hh = (const float*)d_in[14];
  const float* out_w = (const float*)d_in[15];
  const float* out_b = (const float*)d_in[16];
  float* ws = (float*)d_ws;
  float* out = (float*)d_out;
  float* logits = out;                              // [B,T,V]
  float* ht_out = out + (size_t)B * T * V;          // [1,B,H]
  float* attn_out = ht_out + (size_t)B * H;         // [B,T,S]

  hipLaunchKernelGGL(k_init, dim3(64), dim3(256), 0, stream, ehid, tgt, ws);
  // f16 conversions for precompute MFMA
  hipLaunchKernelGGL(k_conv_f16, dim3(1024), dim3(256), 0, stream,
                     keys, 512, 0, (const int*)nullptr, (ushort*)(ws + KEYSH_OFF), 2048);
  hipLaunchKernelGGL(k_conv_f16, dim3(1024), dim3(256), 0, stream,
                     emb, 512, 0, (const int*)(ws + ROWIDX_OFF), (ushort*)(ws + GEH_OFF), 2048);
  hipLaunchKernelGGL(k_conv_f16, dim3(256), dim3(256), 0, stream,
                     Ua_w, 512, 0, (const int*)nullptr, (ushort*)(ws + UAWH_OFF), 512);
  hipLaunchKernelGGL(k_conv_f16, dim3(768), dim3(256), 0, stream,
                     W_ih, 1024, 0, (const int*)nullptr, (ushort*)(ws + WLOH_OFF), 1536);
  hipLaunchKernelGGL(k_conv_f16, dim3(768), dim3(256), 0, stream,
                     W_ih, 1024, 512, (const int*)nullptr, (ushort*)(ws + WCTXH_OFF), 1536);
  // k-major packed f16x2 weights for the recurrence
  hipLaunchKernelGGL(k_pack_t, dim3(512), dim3(256), 0, stream,
                     Wa_w, (unsigned*)(ws + WA2T_OFF), 512);
  hipLaunchKernelGGL(k_pack_t, dim3(1536), dim3(256), 0, stream,
                     W_hh, (unsigned*)(ws + WHH2T_OFF), 1536);
  // UAK = keys @ Ua_w.T + Ua_b  (f16 MFMA)
  hipLaunchKernelGGL(k_mfma128, dim3(4, 16), dim3(256), 0, stream,
                     (const ushort*)(ws + KEYSH_OFF), (const ushort*)(ws + UAWH_OFF),
                     Ua_b, ws + UAK_OFF, 512);
  // GIE = emb[tokens] @ W_ih_lo.T + b_ih  (f16 MFMA)
  hipLaunchKernelGGL(k_mfma128, dim3(12, 16), dim3(256), 0, stream,
                     (const ushort*)(ws + GEH_OFF), (const ushort*)(ws + WLOH_OFF),
                     b_ih, ws + GIE_OFF, G3);
  // KWT (f16 out) = W_ih_ctx @ keys_b^T  (f16 MFMA, per b)
  hipLaunchKernelGGL(k_mfma_kwt, dim3(12, 32), dim3(256), 0, stream,
                     (const ushort*)(ws + WCTXH_OFF), (const ushort*)(ws + KEYSH_OFF),
                     (ushort*)(ws + KWTH_OFF));
  // persistent recurrence
  hipLaunchKernelGGL(k_recur, dim3(256), dim3(256), 0, stream,
                     Wa_b, Va_w, Va_b, b_hh,
                     (const unsigned*)(ws + WA2T_OFF), (const unsigned*)(ws + WHH2T_OFF),
                     ws, attn_out);
  hipLaunchKernelGGL(k_copy_ht, dim3(64), dim3(256), 0, stream,
                     ws + HALL_OFF + (size_t)T * B * H, ht_out);
  // bf16 out_w copy into the (now dead) precompute region
  hipLaunchKernelGGL(k_conv_outw, dim3((V * H / 4 + 255) / 256), dim3(256), 0, stream,
                     out_w, (ushort*)(ws + OWBF_OFF), V * H / 4);
  hipLaunchKernelGGL(k_outgemm, dim3(250, 16), dim3(256), 0, stream,
                     (const __hip_bfloat16*)(ws + HBF_OFF),
                     (const __hip_bfloat16*)(ws + OWBF_OFF), out_b, logits,
                     ws + STATS_OFF);
  hipLaunchKernelGGL(k_lsm_final, dim3(BT), dim3(256), 0, stream,
                     logits, ws + STATS_OFF);
}

// Round 13
// 956.392 us; speedup vs baseline: 1.6189x; 1.0590x over previous
//
#include <hip/hip_runtime.h>
#include <hip/hip_bf16.h>
#include <hip/hip_fp16.h>
#include <math.h>

constexpr int B = 32, S = 64, T = 64, H = 512, V = 32000;
constexpr int G3 = 3 * H;     // 1536
constexpr int BT = B * T;     // 2048

// ---- workspace layout (float slots) ----
constexpr size_t UAK_OFF    = 0;          // f32 [B*S][512]      1,048,576
constexpr size_t GIE_OFF    = 1048576;    // f32 [B*T][1536]     -> 4,194,304
constexpr size_t KWTH_OFF   = 4194304;    // f16 [B][G3][64]     -> 5,767,168
constexpr size_t WA2T_OFF   = 5767168;    // u32 [256][512]      -> 5,898,240
constexpr size_t WHH2T_OFF  = 5898240;    // u32 [256][1536]     -> 6,291,456
constexpr size_t SCPT_OFF   = 6291456;    // f32 [T][B][8][64]   -> 7,340,032
constexpr size_t FLG_OFF    = 7340032;    // int [T][B][32]: [0..7]=h, [8..15]=score
                                          // 65,536 ints -> 7,405,568
constexpr size_t OWBF_OFF   = 0;          // bf16 [V*H] = 8,192,000 slots; aliases all
                                          // of the above (dead after k_recur)
constexpr size_t HALL_OFF   = 8192000;    // f32 [(T+1)*B*H]     -> 9,256,960
constexpr size_t STATS_OFF  = 8192000;    // f32 [2048][512]; reuses HALL (dead after recur+ht)
constexpr size_t HBF_OFF    = 9256960;    // bf16 [B*T*H] -> 9,781,248
// f16 staging for precompute MFMA (dead after precompute)
constexpr size_t KEYSH_OFF  = 10000000;   // f16 [2048][512] -> 10,524,288
constexpr size_t GEH_OFF    = 10524288;   // f16 [2048][512] -> 11,048,576
constexpr size_t UAWH_OFF   = 11048576;   // f16 [512][512]  -> 11,179,648
constexpr size_t WLOH_OFF   = 11179648;   // f16 [1536][512] -> 11,572,864
constexpr size_t WCTXH_OFF  = 11572864;   // f16 [1536][512] -> 11,966,080

typedef __attribute__((ext_vector_type(8))) short bf16x8;
typedef __attribute__((ext_vector_type(4))) float f32x4;
typedef __attribute__((ext_vector_type(4))) int i32x4;
typedef _Float16 f16x8 __attribute__((ext_vector_type(8)));
typedef _Float16 h2v __attribute__((ext_vector_type(2)));

__device__ __forceinline__ float fast_tanh(float x) {
  float ax = fabsf(x);
  float e = __expf(-2.f * ax);
  float r = (1.f - e) / (1.f + e);
  return x < 0.f ? -r : r;
}
__device__ __forceinline__ float fast_sig(float x) {
  return 1.f / (1.f + __expf(-x));
}
__device__ __forceinline__ unsigned pack_h2(float a, float b) {
  __half2 h = __floats2half2_rn(a, b);
  return *(unsigned*)&h;
}
__device__ __forceinline__ ushort f2h(float v) {
  __half h = __float2half(v);
  return *(ushort*)&h;
}
__device__ __forceinline__ void unp2(unsigned v, float* d) {
  __half2 h = *(__half2*)&v;
  d[0] = __low2float(h); d[1] = __high2float(h);
}
__device__ __forceinline__ float dot2acc(unsigned w, unsigned h, float c) {
  return __builtin_amdgcn_fdot2(__builtin_bit_cast(h2v, w),
                                __builtin_bit_cast(h2v, h), c, false);
}
// fused 8-flag coherent poll: both x4 loads in flight, one vmcnt
__device__ __forceinline__ int poll8(const int* p) {
  i32x4 a, b;
  asm volatile("global_load_dwordx4 %0, %2, off sc0 sc1\n\t"
               "global_load_dwordx4 %1, %3, off sc0 sc1\n\t"
               "s_waitcnt vmcnt(0)"
               : "=v"(a), "=v"(b) : "v"(p), "v"(p + 4) : "memory");
  return a.x & a.y & a.z & a.w & b.x & b.y & b.z & b.w;
}
__device__ __forceinline__ void store_coh_i32(int* p, int v) {
  asm volatile("global_store_dword %0, %1, off sc0 sc1" :: "v"(p), "v"(v) : "memory");
}
__device__ __forceinline__ void store_coh_f32(float* p, float v) {
  asm volatile("global_store_dword %0, %1, off sc0 sc1" :: "v"(p), "v"(v) : "memory");
}

// -------------------- consolidated prep: init + f16 convs + k-major packs --------------------
// segments: [0,256) init | [256,1280) keys | [1280,2304) emb-gather | [2304,2560) Ua_w
// | [2560,3328) Wih_lo | [3328,4096) Wih_ctx | [4096,4608) pack Wa | [4608,6144) pack Whh
__global__ void k_prep(const float* __restrict__ eh, const int* __restrict__ tgt,
                       const float* __restrict__ keys, const float* __restrict__ emb,
                       const float* __restrict__ Ua_w, const float* __restrict__ W_ih,
                       const float* __restrict__ Wa_w, const float* __restrict__ W_hh,
                       float* __restrict__ ws) {
  int blk = blockIdx.x, tid = threadIdx.x;
  if (blk < 256) {
    int i = blk * 256 + tid;
    ((int*)(ws + FLG_OFF))[i] = 0;                 // 65536 flags
    if (i < B * H) ws[HALL_OFF + i] = eh[i];
    return;
  }
  if (blk < 1280) {  // keys -> KEYSH f16
    int i4 = ((blk - 256) * 256 + tid) * 4;
    float4 v = *(const float4*)&keys[i4];
    ushort4 o; o.x = f2h(v.x); o.y = f2h(v.y); o.z = f2h(v.z); o.w = f2h(v.w);
    *(ushort4*)&((ushort*)(ws + KEYSH_OFF))[i4] = o;
    return;
  }
  if (blk < 2304) {  // emb[token(row)] -> GEH f16
    int i4 = ((blk - 1280) * 256 + tid) * 4;
    int row = i4 >> 9, k = i4 & 511;
    int tok = (row & 63) ? tgt[row - 1] : 0;       // row = b*64+t; tgt[b*64+t-1]
    float4 v = *(const float4*)&emb[(size_t)tok * 512 + k];
    ushort4 o; o.x = f2h(v.x); o.y = f2h(v.y); o.z = f2h(v.z); o.w = f2h(v.w);
    *(ushort4*)&((ushort*)(ws + GEH_OFF))[i4] = o;
    return;
  }
  if (blk < 2560) {  // Ua_w -> UAWH
    int i4 = ((blk - 2304) * 256 + tid) * 4;
    float4 v = *(const float4*)&Ua_w[i4];
    ushort4 o; o.x = f2h(v.x); o.y = f2h(v.y); o.z = f2h(v.z); o.w = f2h(v.w);
    *(ushort4*)&((ushort*)(ws + UAWH_OFF))[i4] = o;
    return;
  }
  if (blk < 3328) {  // W_ih[:, 0:512] -> WLOH
    int i4 = ((blk - 2560) * 256 + tid) * 4;
    int row = i4 >> 9, k = i4 & 511;
    float4 v = *(const float4*)&W_ih[(size_t)row * 1024 + k];
    ushort4 o; o.x = f2h(v.x); o.y = f2h(v.y); o.z = f2h(v.z); o.w = f2h(v.w);
    *(ushort4*)&((ushort*)(ws + WLOH_OFF))[i4] = o;
    return;
  }
  if (blk < 4096) {  // W_ih[:, 512:1024] -> WCTXH
    int i4 = ((blk - 3328) * 256 + tid) * 4;
    int row = i4 >> 9, k = i4 & 511;
    float4 v = *(const float4*)&W_ih[(size_t)row * 1024 + 512 + k];
    ushort4 o; o.x = f2h(v.x); o.y = f2h(v.y); o.z = f2h(v.z); o.w = f2h(v.w);
    *(ushort4*)&((ushort*)(ws + WCTXH_OFF))[i4] = o;
    return;
  }
  if (blk < 4608) {  // pack Wa k-major [256][512]
    int i = (blk - 4096) * 256 + tid;
    int r = i >> 8, kk = i & 255;
    float2 v = *(const float2*)&Wa_w[(size_t)r * 512 + 2 * kk];
    ((unsigned*)(ws + WA2T_OFF))[(size_t)kk * 512 + r] = pack_h2(v.x, v.y);
    return;
  }
  {                  // pack Whh k-major [256][1536]
    int i = (blk - 4608) * 256 + tid;
    int r = i >> 8, kk = i & 255;
    float2 v = *(const float2*)&W_hh[(size_t)r * 512 + 2 * kk];
    ((unsigned*)(ws + WHH2T_OFF))[(size_t)kk * 1536 + r] = pack_h2(v.x, v.y);
  }
}

// -------------------- out_w fp32 -> bf16 (runs AFTER recurrence; aliases ws) ----
__global__ void k_conv_outw(const float* __restrict__ w, ushort* __restrict__ o, int n4) {
  int i = blockIdx.x * blockDim.x + threadIdx.x;
  if (i < n4) {
    float4 v = *(const float4*)&w[(size_t)i * 4];
    ushort4 u;
    __hip_bfloat16 h0 = __float2bfloat16(v.x); u.x = *(ushort*)&h0;
    __hip_bfloat16 h1 = __float2bfloat16(v.y); u.y = *(ushort*)&h1;
    __hip_bfloat16 h2 = __float2bfloat16(v.z); u.z = *(ushort*)&h2;
    __hip_bfloat16 h3 = __float2bfloat16(v.w); u.w = *(ushort*)&h3;
    *(ushort4*)&o[(size_t)i * 4] = u;
  }
}

// -------- f16 MFMA GEMM 128x128 tiles: C[m*ldc+n] = Ah[m,:].Bh[n,:] + bias[n] --------
__global__ __launch_bounds__(256) void k_mfma128(
    const ushort* __restrict__ Ah, const ushort* __restrict__ Bh,
    const float* __restrict__ bias, float* __restrict__ C, int ldc) {
  __shared__ __align__(16) ushort As[128 * 32];
  __shared__ __align__(16) ushort Bs[128 * 32];
  int bm = blockIdx.y, bn = blockIdx.x;
  int tid = threadIdx.x;
  int lane = tid & 63, wv = tid >> 6;
  int wm = wv >> 1, wn = wv & 1;
  int kc = lane >> 4, rl = lane & 15;
  f32x4 acc[4][4] = {};
  int c0 = wv * 128 + lane, c1 = c0 + 64;
  const ushort* ga0 = Ah + (size_t)(bm * 128 + (c0 >> 2)) * 512 + (c0 & 3) * 8;
  const ushort* ga1 = Ah + (size_t)(bm * 128 + (c1 >> 2)) * 512 + (c1 & 3) * 8;
  const ushort* gb0 = Bh + (size_t)(bn * 128 + (c0 >> 2)) * 512 + (c0 & 3) * 8;
  const ushort* gb1 = Bh + (size_t)(bn * 128 + (c1 >> 2)) * 512 + (c1 & 3) * 8;
  for (int k0 = 0; k0 < 512; k0 += 32) {
    __syncthreads();
    __builtin_amdgcn_global_load_lds(
        (const __attribute__((address_space(1))) void*)(ga0 + k0),
        (__attribute__((address_space(3))) void*)((char*)As + wv * 2048), 16, 0, 0);
    __builtin_amdgcn_global_load_lds(
        (const __attribute__((address_space(1))) void*)(ga1 + k0),
        (__attribute__((address_space(3))) void*)((char*)As + wv * 2048 + 1024), 16, 0, 0);
    __builtin_amdgcn_global_load_lds(
        (const __attribute__((address_space(1))) void*)(gb0 + k0),
        (__attribute__((address_space(3))) void*)((char*)Bs + wv * 2048), 16, 0, 0);
    __builtin_amdgcn_global_load_lds(
        (const __attribute__((address_space(1))) void*)(gb1 + k0),
        (__attribute__((address_space(3))) void*)((char*)Bs + wv * 2048 + 1024), 16, 0, 0);
    __syncthreads();
    f16x8 af[4], bfv[4];
#pragma unroll
    for (int f = 0; f < 4; f++) {
      af[f] = *(const f16x8*)&As[(wm * 64 + f * 16 + rl) * 32 + kc * 8];
      bfv[f] = *(const f16x8*)&Bs[(wn * 64 + f * 16 + rl) * 32 + kc * 8];
    }
#pragma unroll
    for (int i = 0; i < 4; i++)
#pragma unroll
      for (int j = 0; j < 4; j++)
        acc[i][j] = __builtin_amdgcn_mfma_f32_16x16x32_f16(af[i], bfv[j], acc[i][j], 0, 0, 0);
  }
  int cl = lane & 15, rg = lane >> 4;
#pragma unroll
  for (int i = 0; i < 4; i++) {
    int m = bm * 128 + wm * 64 + i * 16 + rg * 4;
#pragma unroll
    for (int j = 0; j < 4; j++) {
      int n = bn * 128 + wn * 64 + j * 16 + cl;
      float bv = bias[n];
#pragma unroll
      for (int r = 0; r < 4; r++)
        C[(size_t)(m + r) * ldc + n] = acc[i][j][r] + bv;
    }
  }
}

// -------- f16 MFMA KWT: per b, [1536 x 64] = Wctx[1536,512] . keys_b[64,512]^T -> f16 --------
__global__ __launch_bounds__(256) void k_mfma_kwt(
    const ushort* __restrict__ Wctxh, const ushort* __restrict__ keysh,
    ushort* __restrict__ KWTh) {
  __shared__ __align__(16) ushort As[128 * 32];
  __shared__ __align__(16) ushort Bs[64 * 32];
  int bm = blockIdx.x, b = blockIdx.y;
  int tid = threadIdx.x;
  int lane = tid & 63, wv = tid >> 6;
  int kc = lane >> 4, rl = lane & 15;
  f32x4 acc[2][4] = {};
  int c0 = tid, c2 = tid + 256;
  const ushort* ga0 = Wctxh + (size_t)(bm * 128 + (c0 >> 2)) * 512 + (c0 & 3) * 8;
  const ushort* ga1 = Wctxh + (size_t)(bm * 128 + (c2 >> 2)) * 512 + (c2 & 3) * 8;
  const ushort* gb0 = keysh + (size_t)(b * 64 + (c0 >> 2)) * 512 + (c0 & 3) * 8;
  for (int k0 = 0; k0 < 512; k0 += 32) {
    __syncthreads();
    __builtin_amdgcn_global_load_lds(
        (const __attribute__((address_space(1))) void*)(ga0 + k0),
        (__attribute__((address_space(3))) void*)((char*)As + wv * 1024), 16, 0, 0);
    __builtin_amdgcn_global_load_lds(
        (const __attribute__((address_space(1))) void*)(ga1 + k0),
        (__attribute__((address_space(3))) void*)((char*)As + 4096 + wv * 1024), 16, 0, 0);
    __builtin_amdgcn_global_load_lds(
        (const __attribute__((address_space(1))) void*)(gb0 + k0),
        (__attribute__((address_space(3))) void*)((char*)Bs + wv * 1024), 16, 0, 0);
    __syncthreads();
    f16x8 af[2], bfv[4];
#pragma unroll
    for (int f = 0; f < 2; f++)
      af[f] = *(const f16x8*)&As[(wv * 32 + f * 16 + rl) * 32 + kc * 8];
#pragma unroll
    for (int j = 0; j < 4; j++)
      bfv[j] = *(const f16x8*)&Bs[(j * 16 + rl) * 32 + kc * 8];
#pragma unroll
    for (int i = 0; i < 2; i++)
#pragma unroll
      for (int j = 0; j < 4; j++)
        acc[i][j] = __builtin_amdgcn_mfma_f32_16x16x32_f16(af[i], bfv[j], acc[i][j], 0, 0, 0);
  }
  int cl = lane & 15, rg = lane >> 4;
#pragma unroll
  for (int i = 0; i < 2; i++) {
    int m = bm * 128 + wv * 32 + i * 16 + rg * 4;
#pragma unroll
    for (int j = 0; j < 4; j++) {
      int n = j * 16 + cl;
#pragma unroll
      for (int r = 0; r < 4; r++)
        KWTh[((size_t)b * G3 + m + r) * 64 + n] = f2h(acc[i][j][r]);
    }
  }
}

// -------------------- persistent recurrence (XCD-co-located, lean handshakes) ----------
// WG w: b = w&31, cb = w>>5. Flags: plain monotone coherent stores (1 word per
// (t,b,cb)), fused x4-pair polls, no sleep. SCP/h published directly from wave-0
// lanes (coherent, coalesced). Final step writes ht_out in place of HALL.
__global__ __launch_bounds__(256) void k_recur(
    const float* __restrict__ Wa_b, const float* __restrict__ Va_w,
    const float* __restrict__ Va_b, const float* __restrict__ b_hh,
    const unsigned* __restrict__ WA2T, const unsigned* __restrict__ WHH2T,
    float* __restrict__ ws, float* __restrict__ attn_out, float* __restrict__ ht_out) {
  const int w = blockIdx.x;
  const int tid = threadIdx.x;
  const int b = w & 31, cb = w >> 5;
  const int j0 = cb * 64;
  int* flg = (int*)(ws + FLG_OFF);
  __hip_bfloat16* HBF = (__hip_bfloat16*)(ws + HBF_OFF);
  const float* GIE = ws + GIE_OFF;
  float* SCPT = ws + SCPT_OFF;
  const ushort* KWTh = (const ushort*)(ws + KWTH_OFF);

  __shared__ float sKWT[192][68];   // 52.2 KB
  __shared__ float sUAK[64][68];    // 17.4 KB
  __shared__ unsigned sH2[256];
  __shared__ float sq[64];
  __shared__ float qp[64][5];
  __shared__ float spp[64][5];
  __shared__ float swt[64];
  __shared__ float sga[4][64];
  __shared__ float sVa[64], sWab[64], sBhh[192];

  // ---- one-time staging ----
#pragma unroll
  for (int g = 0; g < 3; g++) {
    int jl = tid >> 2, part = tid & 3;
    const ushort* src = KWTh + ((size_t)b * G3 + g * 512 + j0 + jl) * 64 + part * 16;
    float* dst = &sKWT[g * 64 + jl][part * 16];
    uint4 u0 = *(const uint4*)src;
    uint4 u1 = *(const uint4*)(src + 8);
    unp2(u0.x, dst); unp2(u0.y, dst + 2); unp2(u0.z, dst + 4); unp2(u0.w, dst + 6);
    unp2(u1.x, dst + 8); unp2(u1.y, dst + 10); unp2(u1.z, dst + 12); unp2(u1.w, dst + 14);
  }
  {
    int s = tid >> 2, part = tid & 3;
    const float* src = ws + UAK_OFF + ((size_t)(b * 64 + s)) * 512 + j0 + part * 16;
    float* dst = &sUAK[s][part * 16];
#pragma unroll
    for (int i = 0; i < 16; i += 4) *(float4*)&dst[i] = *(const float4*)&src[i];
  }
  if (tid < 64) { sVa[tid] = Va_w[j0 + tid]; sWab[tid] = Wa_b[j0 + tid]; }
  if (tid < 192) sBhh[tid] = b_hh[(tid >> 6) * 512 + j0 + (tid & 63)];
  const float va_b = Va_b[0];
  __syncthreads();

  for (int t = 0; t < T; ++t) {
    const float* hcur = ws + HALL_OFF + (size_t)t * B * H + b * H;
    // GIE prefetch (independent of h) issues before the wait
    float gival = 0.f;
    if (tid < 192)
      gival = GIE[((size_t)b * T + t) * G3 + (tid >> 6) * 512 + j0 + (tid & 63)];
    // ---- wait for h_t ----
    if (t > 0) {
      if (tid == 0) {
        const int* fb = flg + (size_t)(t - 1) * 1024 + b * 32;
        while (!poll8(fb)) {}
      }
    }
    __syncthreads();
    // stage h as packed f16 pairs (float2 per thread, coalesced)
    {
      float2 h2 = *(const float2*)&hcur[2 * tid];
      sH2[tid] = pack_h2(h2.x, h2.y);
    }
    __syncthreads();

    // ---- q slice (coalesced k-major f16) ----
    {
      int jq = tid & 63, kp = tid >> 6;
      const unsigned* wp = WA2T + (size_t)(kp * 64) * 512 + j0 + jq;
      float acc = 0.f;
#pragma unroll 8
      for (int kk = 0; kk < 64; kk++)
        acc = dot2acc(wp[(size_t)kk * 512], sH2[kp * 64 + kk], acc);
      qp[jq][kp] = acc;
    }
    __syncthreads();
    if (tid < 64)
      sq[tid] = qp[tid][0] + qp[tid][1] + qp[tid][2] + qp[tid][3] + sWab[tid];
    __syncthreads();
    // ---- score partials over this WG's 64-j slice ----
    {
      int s = tid >> 2, jc = tid & 3;
      float accs = 0.f;
#pragma unroll
      for (int i = 0; i < 16; i++) {
        int j = jc * 16 + i;
        accs += sVa[j] * fast_tanh(sq[j] + sUAK[s][j]);
      }
      spp[s][jc] = accs;
    }
    __syncthreads();
    if (tid < 64) {
      float v = spp[tid][0] + spp[tid][1] + spp[tid][2] + spp[tid][3];
      if (cb == 0) v += va_b;
      store_coh_f32(SCPT + (((size_t)t * B + b) * 8 + cb) * 64 + tid, v);
    }
    if (tid == 0) {
      asm volatile("s_waitcnt vmcnt(0)" ::: "memory");
      store_coh_i32(flg + (size_t)t * 1024 + b * 32 + 8 + cb, 1);
    }

    // ---- gh (coalesced k-major f16), overlaps peers' score phase ----
    float gh = 0.f;
    if (tid < 192) {
      int gate = tid >> 6, lane = tid & 63;
      const unsigned* wp = WHH2T + gate * 512 + j0 + lane;
      float g0 = 0.f, g1 = 0.f;
#pragma unroll 8
      for (int kk = 0; kk < 256; kk += 2) {
        g0 = dot2acc(wp[(size_t)kk * 1536], sH2[kk], g0);
        g1 = dot2acc(wp[(size_t)(kk + 1) * 1536], sH2[kk + 1], g1);
      }
      gh = g0 + g1 + sBhh[tid];
    }
    // ---- wait all 8 score slices of batch b ----
    if (tid == 0) {
      const int* fs = flg + (size_t)t * 1024 + b * 32 + 8;
      while (!poll8(fs)) {}
    }
    __syncthreads();
    // ---- direct 8-slice reduce (plain first-touch loads) + softmax ----
    if (tid < 64) {
      const float* sp = SCPT + ((size_t)t * B + b) * 512;
      float v = (sp[tid] + sp[64 + tid]) + (sp[128 + tid] + sp[192 + tid])
              + (sp[256 + tid] + sp[320 + tid]) + (sp[384 + tid] + sp[448 + tid]);
      float m = v;
      for (int o = 32; o; o >>= 1) m = fmaxf(m, __shfl_xor(m, o, 64));
      float e = __expf(v - m);
      float su = e;
      for (int o = 32; o; o >>= 1) su += __shfl_xor(su, o, 64);
      float wt = e / su;
      swt[tid] = wt;
      if (cb == 0) attn_out[((size_t)b * T + t) * S + tid] = wt;
    }
    __syncthreads();
    // ---- gic = KWT . wt (LDS f32) ; combine ----
    if (tid < 192) {
      int gate = tid >> 6, lane = tid & 63;
      float gic = 0.f;
#pragma unroll
      for (int s4 = 0; s4 < 64; s4 += 4) {
        float4 k4 = *(const float4*)&sKWT[tid][s4];
        gic += k4.x * swt[s4] + k4.y * swt[s4 + 1] + k4.z * swt[s4 + 2] + k4.w * swt[s4 + 3];
      }
      float gi = gival + gic;
      if (gate == 0) sga[0][lane] = gi + gh;
      else if (gate == 1) sga[1][lane] = gi + gh;
      else { sga[2][lane] = gi; sga[3][lane] = gh; }
    }
    __syncthreads();
    // ---- GRU update + direct publish ----
    if (tid < 64) {
      float r = fast_sig(sga[0][tid]);
      float z = fast_sig(sga[1][tid]);
      float n = fast_tanh(sga[2][tid] + r * sga[3][tid]);
      float hold = hcur[j0 + tid];                // L1/L2-hot from staging
      float hn = (1.f - z) * n + z * hold;
      HBF[((size_t)b * T + t) * H + j0 + tid] = __float2bfloat16(hn);
      if (t < T - 1)
        store_coh_f32(ws + HALL_OFF + (size_t)(t + 1) * B * H + b * H + j0 + tid, hn);
      else
        ht_out[b * H + j0 + tid] = hn;            // plain: kernel-end flush
    }
    if (tid == 0 && t < T - 1) {
      asm volatile("s_waitcnt vmcnt(0)" ::: "memory");
      store_coh_i32(flg + (size_t)t * 1024 + b * 32 + cb, 1);
    }
    __syncthreads();   // protect LDS reuse before next iteration
  }
}

// -------- bf16 MFMA out-projection w/ global_load_lds + fused softmax stats --------
__global__ __launch_bounds__(256) void k_outgemm(
    const __hip_bfloat16* __restrict__ Abf, const __hip_bfloat16* __restrict__ Bbf,
    const float* __restrict__ bias, float* __restrict__ Cmat,
    float* __restrict__ stats) {
  __shared__ __align__(16) short As[128 * 32];
  __shared__ __align__(16) short Bs[128 * 32];
  __shared__ float sredM[2][128];
  __shared__ float sredS[2][128];
  int bm = blockIdx.y, bn = blockIdx.x;
  int tid = threadIdx.x;
  int lane = tid & 63, wv = tid >> 6;
  int wm = wv >> 1, wn = wv & 1;
  int kc = lane >> 4, rl = lane & 15;
  f32x4 acc[4][4] = {};
  int c0 = wv * 128 + lane, c1 = c0 + 64;
  const __hip_bfloat16* ga0 = Abf + (size_t)(bm * 128 + (c0 >> 2)) * 512 + (c0 & 3) * 8;
  const __hip_bfloat16* ga1 = Abf + (size_t)(bm * 128 + (c1 >> 2)) * 512 + (c1 & 3) * 8;
  const __hip_bfloat16* gb0 = Bbf + (size_t)(bn * 128 + (c0 >> 2)) * 512 + (c0 & 3) * 8;
  const __hip_bfloat16* gb1 = Bbf + (size_t)(bn * 128 + (c1 >> 2)) * 512 + (c1 & 3) * 8;
  for (int k0 = 0; k0 < 512; k0 += 32) {
    __syncthreads();
    __builtin_amdgcn_global_load_lds(
        (const __attribute__((address_space(1))) void*)(ga0 + k0),
        (__attribute__((address_space(3))) void*)((char*)As + wv * 2048), 16, 0, 0);
    __builtin_amdgcn_global_load_lds(
        (const __attribute__((address_space(1))) void*)(ga1 + k0),
        (__attribute__((address_space(3))) void*)((char*)As + wv * 2048 + 1024), 16, 0, 0);
    __builtin_amdgcn_global_load_lds(
        (const __attribute__((address_space(1))) void*)(gb0 + k0),
        (__attribute__((address_space(3))) void*)((char*)Bs + wv * 2048), 16, 0, 0);
    __builtin_amdgcn_global_load_lds(
        (const __attribute__((address_space(1))) void*)(gb1 + k0),
        (__attribute__((address_space(3))) void*)((char*)Bs + wv * 2048 + 1024), 16, 0, 0);
    __syncthreads();
    bf16x8 af[4], bfv[4];
#pragma unroll
    for (int f = 0; f < 4; f++) {
      af[f] = *(const bf16x8*)&As[(wm * 64 + f * 16 + rl) * 32 + kc * 8];
      bfv[f] = *(const bf16x8*)&Bs[(wn * 64 + f * 16 + rl) * 32 + kc * 8];
    }
#pragma unroll
    for (int i = 0; i < 4; i++)
#pragma unroll
      for (int j = 0; j < 4; j++)
        acc[i][j] = __builtin_amdgcn_mfma_f32_16x16x32_bf16(af[i], bfv[j], acc[i][j], 0, 0, 0);
  }
  int cl = lane & 15, rg = lane >> 4;
  float bv[4];
#pragma unroll
  for (int j = 0; j < 4; j++) bv[j] = bias[bn * 128 + wn * 64 + j * 16 + cl];
  float vmax[4][4];
#pragma unroll
  for (int i = 0; i < 4; i++) {
    int m = bm * 128 + wm * 64 + i * 16 + rg * 4;
#pragma unroll
    for (int r = 0; r < 4; r++) vmax[i][r] = -1e30f;
#pragma unroll
    for (int j = 0; j < 4; j++) {
      int n = bn * 128 + wn * 64 + j * 16 + cl;
#pragma unroll
      for (int r = 0; r < 4; r++) {
        float val = acc[i][j][r] + bv[j];
        Cmat[(size_t)(m + r) * V + n] = val;
        vmax[i][r] = fmaxf(vmax[i][r], val);
      }
    }
  }
#pragma unroll
  for (int o = 1; o < 16; o <<= 1)
#pragma unroll
    for (int i = 0; i < 4; i++)
#pragma unroll
      for (int r = 0; r < 4; r++)
        vmax[i][r] = fmaxf(vmax[i][r], __shfl_xor(vmax[i][r], o, 64));
  float vsum[4][4] = {};
#pragma unroll
  for (int i = 0; i < 4; i++)
#pragma unroll
    for (int j = 0; j < 4; j++)
#pragma unroll
      for (int r = 0; r < 4; r++)
        vsum[i][r] += __expf(acc[i][j][r] + bv[j] - vmax[i][r]);
#pragma unroll
  for (int o = 1; o < 16; o <<= 1)
#pragma unroll
    for (int i = 0; i < 4; i++)
#pragma unroll
      for (int r = 0; r < 4; r++)
        vsum[i][r] += __shfl_xor(vsum[i][r], o, 64);
  if (cl == 0) {
#pragma unroll
    for (int i = 0; i < 4; i++)
#pragma unroll
      for (int r = 0; r < 4; r++) {
        int rowl = wm * 64 + i * 16 + rg * 4 + r;
        sredM[wn][rowl] = vmax[i][r];
        sredS[wn][rowl] = vsum[i][r];
      }
  }
  __syncthreads();
  if (tid < 128) {
    float m0 = sredM[0][tid], m1 = sredM[1][tid];
    float M = fmaxf(m0, m1);
    float Sv = sredS[0][tid] * __expf(m0 - M) + sredS[1][tid] * __expf(m1 - M);
    float* st = stats + (size_t)(bm * 128 + tid) * 512 + bn * 2;
    st[0] = M; st[1] = Sv;
  }
}

// -------------------- final pass: lse from stats, subtract in-place --------------------
__global__ __launch_bounds__(256) void k_lsm_final(float* __restrict__ Cmat,
                                                   const float* __restrict__ stats) {
  int row = blockIdx.x;
  int tid = threadIdx.x;
  __shared__ float sM[4], sS[4];
  float m = -1e30f, s = 0.f;
  if (tid < 250) {
    float2 v = *(const float2*)&stats[(size_t)row * 512 + tid * 2];
    m = v.x; s = v.y;
  }
  for (int o = 32; o; o >>= 1) {
    float om = __shfl_xor(m, o, 64), os = __shfl_xor(s, o, 64);
    float nm = fmaxf(m, om);
    s = s * __expf(m - nm) + os * __expf(om - nm);
    m = nm;
  }
  if ((tid & 63) == 0) { sM[tid >> 6] = m; sS[tid >> 6] = s; }
  __syncthreads();
  float M = fmaxf(fmaxf(sM[0], sM[1]), fmaxf(sM[2], sM[3]));
  float Ssum = sS[0] * __expf(sM[0] - M) + sS[1] * __expf(sM[1] - M)
             + sS[2] * __expf(sM[2] - M) + sS[3] * __expf(sM[3] - M);
  float lse = M + __logf(Ssum);
  float* p = Cmat + (size_t)row * V;
  for (int i = tid * 4; i < V; i += 1024) {
    float4 v = *(const float4*)&p[i];
    v.x -= lse; v.y -= lse; v.z -= lse; v.w -= lse;
    *(float4*)&p[i] = v;
  }
}

extern "C" void kernel_launch(void* const* d_in, const int* in_sizes, int n_in,
                              void* d_out, int out_size, void* d_ws, size_t ws_size,
                              hipStream_t stream) {
  (void)in_sizes; (void)n_in; (void)out_size; (void)ws_size;
  const float* keys = (const float*)d_in[0];
  const float* ehid = (const float*)d_in[1];
  const int* tgt    = (const int*)d_in[2];
  const float* emb  = (const float*)d_in[4];
  const float* Wa_w = (const float*)d_in[5];
  const float* Wa_b = (const float*)d_in[6];
  const float* Ua_w = (const float*)d_in[7];
  const float* Ua_b = (const float*)d_in[8];
  const float* Va_w = (const float*)d_in[9];
  const float* Va_b = (const float*)d_in[10];
  const float* W_ih = (const float*)d_in[11];
  const float* W_hh = (const float*)d_in[12];
  const float* b_ih = (const float*)d_in[13];
  const float* b_hh = (const float*)d_in[14];
  const float* out_w = (const float*)d_in[15];
  const float* out_b = (const float*)d_in[16];
  float* ws = (float*)d_ws;
  float* out = (float*)d_out;
  float* logits = out;                              // [B,T,V]
  float* ht_out = out + (size_t)B * T * V;          // [1,B,H]
  float* attn_out = ht_out + (size_t)B * H;         // [B,T,S]

  // consolidated prep (init + f16 convs + packs)
  hipLaunchKernelGGL(k_prep, dim3(6144), dim3(256), 0, stream,
                     ehid, tgt, keys, emb, Ua_w, W_ih, Wa_w, W_hh, ws);
  // UAK = keys @ Ua_w.T + Ua_b  (f16 MFMA)
  hipLaunchKernelGGL(k_mfma128, dim3(4, 16), dim3(256), 0, stream,
                     (const ushort*)(ws + KEYSH_OFF), (const ushort*)(ws + UAWH_OFF),
                     Ua_b, ws + UAK_OFF, 512);
  // GIE = emb[tokens] @ W_ih_lo.T + b_ih  (f16 MFMA)
  hipLaunchKernelGGL(k_mfma128, dim3(12, 16), dim3(256), 0, stream,
                     (const ushort*)(ws + GEH_OFF), (const ushort*)(ws + WLOH_OFF),
                     b_ih, ws + GIE_OFF, G3);
  // KWT (f16 out) = W_ih_ctx @ keys_b^T  (f16 MFMA, per b)
  hipLaunchKernelGGL(k_mfma_kwt, dim3(12, 32), dim3(256), 0, stream,
                     (const ushort*)(ws + WCTXH_OFF), (const ushort*)(ws + KEYSH_OFF),
                     (ushort*)(ws + KWTH_OFF));
  // persistent recurrence (writes ht_out at final step)
  hipLaunchKernelGGL(k_recur, dim3(256), dim3(256), 0, stream,
                     Wa_b, Va_w, Va_b, b_hh,
                     (const unsigned*)(ws + WA2T_OFF), (const unsigned*)(ws + WHH2T_OFF),
                     ws, attn_out, ht_out);
  // bf16 out_w copy into the (now dead) precompute region
  hipLaunchKernelGGL(k_conv_outw, dim3((V * H / 4 + 255) / 256), dim3(256), 0, stream,
                     out_w, (ushort*)(ws + OWBF_OFF), V * H / 4);
  hipLaunchKernelGGL(k_outgemm, dim3(250, 16), dim3(256), 0, stream,
                     (const __hip_bfloat16*)(ws + HBF_OFF),
                     (const __hip_bfloat16*)(ws + OWBF_OFF), out_b, logits,
                     ws + STATS_OFF);
  hipLaunchKernelGGL(k_lsm_final, dim3(BT), dim3(256), 0, stream,
                     logits, ws + STATS_OFF);
}

// Round 14
// 940.596 us; speedup vs baseline: 1.6461x; 1.0168x over previous
//
#include <hip/hip_runtime.h>
#include <hip/hip_bf16.h>
#include <hip/hip_fp16.h>
#include <math.h>

constexpr int B = 32, S = 64, T = 64, H = 512, V = 32000;
constexpr int G3 = 3 * H;     // 1536
constexpr int BT = B * T;     // 2048

// ---- workspace layout (float slots) ----
constexpr size_t UAK_OFF    = 0;          // f32 [B*S][512]      1,048,576
constexpr size_t GIE_OFF    = 1048576;    // f32 [B*T][1536]     -> 4,194,304
constexpr size_t KWTH_OFF   = 4194304;    // f16 [B][G3][64]     -> 5,767,168
constexpr size_t WA2T_OFF   = 5767168;    // u32 [256][512]      -> 5,898,240
constexpr size_t WHH2T_OFF  = 5898240;    // u32 [256][1536]     -> 6,291,456
constexpr size_t SCPT_OFF   = 6291456;    // f32 [T][B][8][64]   -> 7,340,032
constexpr size_t FLG_OFF    = 7340032;    // int [T][B][32]: [0..7]=hS [8..15]=sS
                                          // [16..23]=hF [24..31]=sF -> 7,405,568
constexpr size_t OWBF_OFF   = 0;          // bf16 [V*H] = 8,192,000 slots; aliases all
                                          // of the above (dead after k_recur)
constexpr size_t HALL_OFF   = 8192000;    // f32 [(T+1)*B*H]     -> 9,256,960
constexpr size_t STATS_OFF  = 8192000;    // f32 [2048][512]; reuses HALL (dead after recur)
constexpr size_t HBF_OFF    = 9256960;    // bf16 [B*T*H] -> 9,781,248
// f16 staging for precompute MFMA (dead after precompute)
constexpr size_t KEYSH_OFF  = 10000000;   // f16 [2048][512] -> 10,524,288
constexpr size_t GEH_OFF    = 10524288;   // f16 [2048][512] -> 11,048,576
constexpr size_t UAWH_OFF   = 11048576;   // f16 [512][512]  -> 11,179,648
constexpr size_t WLOH_OFF   = 11179648;   // f16 [1536][512] -> 11,572,864
constexpr size_t WCTXH_OFF  = 11572864;   // f16 [1536][512] -> 11,966,080

typedef __attribute__((ext_vector_type(8))) short bf16x8;
typedef __attribute__((ext_vector_type(4))) float f32x4;
typedef __attribute__((ext_vector_type(4))) int i32x4;
typedef _Float16 f16x8 __attribute__((ext_vector_type(8)));
typedef _Float16 h2v __attribute__((ext_vector_type(2)));

__device__ __forceinline__ float fast_tanh(float x) {
  float ax = fabsf(x);
  float e = __expf(-2.f * ax);
  float r = (1.f - e) / (1.f + e);
  return x < 0.f ? -r : r;
}
__device__ __forceinline__ float fast_sig(float x) {
  return 1.f / (1.f + __expf(-x));
}
__device__ __forceinline__ unsigned pack_h2(float a, float b) {
  __half2 h = __floats2half2_rn(a, b);
  return *(unsigned*)&h;
}
__device__ __forceinline__ ushort f2h(float v) {
  __half h = __float2half(v);
  return *(ushort*)&h;
}
__device__ __forceinline__ void unp2(unsigned v, float* d) {
  __half2 h = *(__half2*)&v;
  d[0] = __low2float(h); d[1] = __high2float(h);
}
__device__ __forceinline__ float dot2acc(unsigned w, unsigned h, float c) {
  return __builtin_amdgcn_fdot2(__builtin_bit_cast(h2v, w),
                                __builtin_bit_cast(h2v, h), c, false);
}
// slow poll: coherence-point (LLC) — always correct
__device__ __forceinline__ int poll8_coh(const int* p) {
  i32x4 a, b;
  asm volatile("global_load_dwordx4 %0, %2, off sc0 sc1\n\t"
               "global_load_dwordx4 %1, %3, off sc0 sc1\n\t"
               "s_waitcnt vmcnt(0)"
               : "=v"(a), "=v"(b) : "v"(p), "v"(p + 4) : "memory");
  return a.x & a.y & a.z & a.w & b.x & b.y & b.z & b.w;
}
// fast poll: bypass L1, read (shared) L2 — fires when producer co-located
__device__ __forceinline__ int poll8_l2(const int* p) {
  i32x4 a, b;
  asm volatile("global_load_dwordx4 %0, %2, off sc0\n\t"
               "global_load_dwordx4 %1, %3, off sc0\n\t"
               "s_waitcnt vmcnt(0)"
               : "=v"(a), "=v"(b) : "v"(p), "v"(p + 4) : "memory");
  return a.x & a.y & a.z & a.w & b.x & b.y & b.z & b.w;
}
__device__ __forceinline__ void store_coh_i32(int* p, int v) {
  asm volatile("global_store_dword %0, %1, off sc0 sc1" :: "v"(p), "v"(v) : "memory");
}
__device__ __forceinline__ void store_plain_i32(int* p, int v) {
  asm volatile("global_store_dword %0, %1, off" :: "v"(p), "v"(v) : "memory");
}
__device__ __forceinline__ void store_coh_f32(float* p, float v) {
  asm volatile("global_store_dword %0, %1, off sc0 sc1" :: "v"(p), "v"(v) : "memory");
}

// -------------------- consolidated prep: init + f16 convs + k-major packs --------------------
__global__ void k_prep(const float* __restrict__ eh, const int* __restrict__ tgt,
                       const float* __restrict__ keys, const float* __restrict__ emb,
                       const float* __restrict__ Ua_w, const float* __restrict__ W_ih,
                       const float* __restrict__ Wa_w, const float* __restrict__ W_hh,
                       float* __restrict__ ws) {
  int blk = blockIdx.x, tid = threadIdx.x;
  if (blk < 256) {
    int i = blk * 256 + tid;
    ((int*)(ws + FLG_OFF))[i] = 0;                 // 65536 flags
    if (i < B * H) ws[HALL_OFF + i] = eh[i];
    return;
  }
  if (blk < 1280) {  // keys -> KEYSH f16
    int i4 = ((blk - 256) * 256 + tid) * 4;
    float4 v = *(const float4*)&keys[i4];
    ushort4 o; o.x = f2h(v.x); o.y = f2h(v.y); o.z = f2h(v.z); o.w = f2h(v.w);
    *(ushort4*)&((ushort*)(ws + KEYSH_OFF))[i4] = o;
    return;
  }
  if (blk < 2304) {  // emb[token(row)] -> GEH f16
    int i4 = ((blk - 1280) * 256 + tid) * 4;
    int row = i4 >> 9, k = i4 & 511;
    int tok = (row & 63) ? tgt[row - 1] : 0;
    float4 v = *(const float4*)&emb[(size_t)tok * 512 + k];
    ushort4 o; o.x = f2h(v.x); o.y = f2h(v.y); o.z = f2h(v.z); o.w = f2h(v.w);
    *(ushort4*)&((ushort*)(ws + GEH_OFF))[i4] = o;
    return;
  }
  if (blk < 2560) {  // Ua_w -> UAWH
    int i4 = ((blk - 2304) * 256 + tid) * 4;
    float4 v = *(const float4*)&Ua_w[i4];
    ushort4 o; o.x = f2h(v.x); o.y = f2h(v.y); o.z = f2h(v.z); o.w = f2h(v.w);
    *(ushort4*)&((ushort*)(ws + UAWH_OFF))[i4] = o;
    return;
  }
  if (blk < 3328) {  // W_ih[:, 0:512] -> WLOH
    int i4 = ((blk - 2560) * 256 + tid) * 4;
    int row = i4 >> 9, k = i4 & 511;
    float4 v = *(const float4*)&W_ih[(size_t)row * 1024 + k];
    ushort4 o; o.x = f2h(v.x); o.y = f2h(v.y); o.z = f2h(v.z); o.w = f2h(v.w);
    *(ushort4*)&((ushort*)(ws + WLOH_OFF))[i4] = o;
    return;
  }
  if (blk < 4096) {  // W_ih[:, 512:1024] -> WCTXH
    int i4 = ((blk - 3328) * 256 + tid) * 4;
    int row = i4 >> 9, k = i4 & 511;
    float4 v = *(const float4*)&W_ih[(size_t)row * 1024 + 512 + k];
    ushort4 o; o.x = f2h(v.x); o.y = f2h(v.y); o.z = f2h(v.z); o.w = f2h(v.w);
    *(ushort4*)&((ushort*)(ws + WCTXH_OFF))[i4] = o;
    return;
  }
  if (blk < 4608) {  // pack Wa k-major [256][512]
    int i = (blk - 4096) * 256 + tid;
    int r = i >> 8, kk = i & 255;
    float2 v = *(const float2*)&Wa_w[(size_t)r * 512 + 2 * kk];
    ((unsigned*)(ws + WA2T_OFF))[(size_t)kk * 512 + r] = pack_h2(v.x, v.y);
    return;
  }
  {                  // pack Whh k-major [256][1536]
    int i = (blk - 4608) * 256 + tid;
    int r = i >> 8, kk = i & 255;
    float2 v = *(const float2*)&W_hh[(size_t)r * 512 + 2 * kk];
    ((unsigned*)(ws + WHH2T_OFF))[(size_t)kk * 1536 + r] = pack_h2(v.x, v.y);
  }
}

// -------------------- out_w fp32 -> bf16 (runs AFTER recurrence; aliases ws) ----
__global__ void k_conv_outw(const float* __restrict__ w, ushort* __restrict__ o, int n4) {
  int i = blockIdx.x * blockDim.x + threadIdx.x;
  if (i < n4) {
    float4 v = *(const float4*)&w[(size_t)i * 4];
    ushort4 u;
    __hip_bfloat16 h0 = __float2bfloat16(v.x); u.x = *(ushort*)&h0;
    __hip_bfloat16 h1 = __float2bfloat16(v.y); u.y = *(ushort*)&h1;
    __hip_bfloat16 h2 = __float2bfloat16(v.z); u.z = *(ushort*)&h2;
    __hip_bfloat16 h3 = __float2bfloat16(v.w); u.w = *(ushort*)&h3;
    *(ushort4*)&o[(size_t)i * 4] = u;
  }
}

// -------- f16 MFMA GEMM 128x128 tiles: C[m*ldc+n] = Ah[m,:].Bh[n,:] + bias[n] --------
__global__ __launch_bounds__(256) void k_mfma128(
    const ushort* __restrict__ Ah, const ushort* __restrict__ Bh,
    const float* __restrict__ bias, float* __restrict__ C, int ldc) {
  __shared__ __align__(16) ushort As[128 * 32];
  __shared__ __align__(16) ushort Bs[128 * 32];
  int bm = blockIdx.y, bn = blockIdx.x;
  int tid = threadIdx.x;
  int lane = tid & 63, wv = tid >> 6;
  int wm = wv >> 1, wn = wv & 1;
  int kc = lane >> 4, rl = lane & 15;
  f32x4 acc[4][4] = {};
  int c0 = wv * 128 + lane, c1 = c0 + 64;
  const ushort* ga0 = Ah + (size_t)(bm * 128 + (c0 >> 2)) * 512 + (c0 & 3) * 8;
  const ushort* ga1 = Ah + (size_t)(bm * 128 + (c1 >> 2)) * 512 + (c1 & 3) * 8;
  const ushort* gb0 = Bh + (size_t)(bn * 128 + (c0 >> 2)) * 512 + (c0 & 3) * 8;
  const ushort* gb1 = Bh + (size_t)(bn * 128 + (c1 >> 2)) * 512 + (c1 & 3) * 8;
  for (int k0 = 0; k0 < 512; k0 += 32) {
    __syncthreads();
    __builtin_amdgcn_global_load_lds(
        (const __attribute__((address_space(1))) void*)(ga0 + k0),
        (__attribute__((address_space(3))) void*)((char*)As + wv * 2048), 16, 0, 0);
    __builtin_amdgcn_global_load_lds(
        (const __attribute__((address_space(1))) void*)(ga1 + k0),
        (__attribute__((address_space(3))) void*)((char*)As + wv * 2048 + 1024), 16, 0, 0);
    __builtin_amdgcn_global_load_lds(
        (const __attribute__((address_space(1))) void*)(gb0 + k0),
        (__attribute__((address_space(3))) void*)((char*)Bs + wv * 2048), 16, 0, 0);
    __builtin_amdgcn_global_load_lds(
        (const __attribute__((address_space(1))) void*)(gb1 + k0),
        (__attribute__((address_space(3))) void*)((char*)Bs + wv * 2048 + 1024), 16, 0, 0);
    __syncthreads();
    f16x8 af[4], bfv[4];
#pragma unroll
    for (int f = 0; f < 4; f++) {
      af[f] = *(const f16x8*)&As[(wm * 64 + f * 16 + rl) * 32 + kc * 8];
      bfv[f] = *(const f16x8*)&Bs[(wn * 64 + f * 16 + rl) * 32 + kc * 8];
    }
#pragma unroll
    for (int i = 0; i < 4; i++)
#pragma unroll
      for (int j = 0; j < 4; j++)
        acc[i][j] = __builtin_amdgcn_mfma_f32_16x16x32_f16(af[i], bfv[j], acc[i][j], 0, 0, 0);
  }
  int cl = lane & 15, rg = lane >> 4;
#pragma unroll
  for (int i = 0; i < 4; i++) {
    int m = bm * 128 + wm * 64 + i * 16 + rg * 4;
#pragma unroll
    for (int j = 0; j < 4; j++) {
      int n = bn * 128 + wn * 64 + j * 16 + cl;
      float bv = bias[n];
#pragma unroll
      for (int r = 0; r < 4; r++)
        C[(size_t)(m + r) * ldc + n] = acc[i][j][r] + bv;
    }
  }
}

// -------- f16 MFMA KWT: per b, [1536 x 64] = Wctx[1536,512] . keys_b[64,512]^T -> f16 --------
__global__ __launch_bounds__(256) void k_mfma_kwt(
    const ushort* __restrict__ Wctxh, const ushort* __restrict__ keysh,
    ushort* __restrict__ KWTh) {
  __shared__ __align__(16) ushort As[128 * 32];
  __shared__ __align__(16) ushort Bs[64 * 32];
  int bm = blockIdx.x, b = blockIdx.y;
  int tid = threadIdx.x;
  int lane = tid & 63, wv = tid >> 6;
  int kc = lane >> 4, rl = lane & 15;
  f32x4 acc[2][4] = {};
  int c0 = tid, c2 = tid + 256;
  const ushort* ga0 = Wctxh + (size_t)(bm * 128 + (c0 >> 2)) * 512 + (c0 & 3) * 8;
  const ushort* ga1 = Wctxh + (size_t)(bm * 128 + (c2 >> 2)) * 512 + (c2 & 3) * 8;
  const ushort* gb0 = keysh + (size_t)(b * 64 + (c0 >> 2)) * 512 + (c0 & 3) * 8;
  for (int k0 = 0; k0 < 512; k0 += 32) {
    __syncthreads();
    __builtin_amdgcn_global_load_lds(
        (const __attribute__((address_space(1))) void*)(ga0 + k0),
        (__attribute__((address_space(3))) void*)((char*)As + wv * 1024), 16, 0, 0);
    __builtin_amdgcn_global_load_lds(
        (const __attribute__((address_space(1))) void*)(ga1 + k0),
        (__attribute__((address_space(3))) void*)((char*)As + 4096 + wv * 1024), 16, 0, 0);
    __builtin_amdgcn_global_load_lds(
        (const __attribute__((address_space(1))) void*)(gb0 + k0),
        (__attribute__((address_space(3))) void*)((char*)Bs + wv * 1024), 16, 0, 0);
    __syncthreads();
    f16x8 af[2], bfv[4];
#pragma unroll
    for (int f = 0; f < 2; f++)
      af[f] = *(const f16x8*)&As[(wv * 32 + f * 16 + rl) * 32 + kc * 8];
#pragma unroll
    for (int j = 0; j < 4; j++)
      bfv[j] = *(const f16x8*)&Bs[(j * 16 + rl) * 32 + kc * 8];
#pragma unroll
    for (int i = 0; i < 2; i++)
#pragma unroll
      for (int j = 0; j < 4; j++)
        acc[i][j] = __builtin_amdgcn_mfma_f32_16x16x32_f16(af[i], bfv[j], acc[i][j], 0, 0, 0);
  }
  int cl = lane & 15, rg = lane >> 4;
#pragma unroll
  for (int i = 0; i < 2; i++) {
    int m = bm * 128 + wv * 32 + i * 16 + rg * 4;
#pragma unroll
    for (int j = 0; j < 4; j++) {
      int n = j * 16 + cl;
#pragma unroll
      for (int r = 0; r < 4; r++)
        KWTh[((size_t)b * G3 + m + r) * 64 + n] = f2h(acc[i][j][r]);
    }
  }
}

// -------------------- persistent recurrence (dual-flag fast/slow handshakes) ----------
// WG w: b = w&31, cb = w>>5 (8 WGs of a batch co-locate on one XCD under round-robin).
// Producer publishes each flag twice: plain store (visible in shared L2 fast) and
// sc0sc1 store (LLC, always works). Consumer alternates sc0-only poll (shared L2)
// with sc0sc1 poll (LLC). Data stores remain sc0sc1 + vmcnt before flags -> any
// flag sighting implies data is readable (L2-fresh or LLC-fresh, first-touch).
__global__ __launch_bounds__(256) void k_recur(
    const float* __restrict__ Wa_b, const float* __restrict__ Va_w,
    const float* __restrict__ Va_b, const float* __restrict__ b_hh,
    const unsigned* __restrict__ WA2T, const unsigned* __restrict__ WHH2T,
    float* __restrict__ ws, float* __restrict__ attn_out, float* __restrict__ ht_out) {
  const int w = blockIdx.x;
  const int tid = threadIdx.x;
  const int b = w & 31, cb = w >> 5;
  const int j0 = cb * 64;
  int* flg = (int*)(ws + FLG_OFF);
  __hip_bfloat16* HBF = (__hip_bfloat16*)(ws + HBF_OFF);
  const float* GIE = ws + GIE_OFF;
  float* SCPT = ws + SCPT_OFF;
  const ushort* KWTh = (const ushort*)(ws + KWTH_OFF);

  __shared__ float sKWT[192][68];   // 52.2 KB
  __shared__ float sUAK[64][68];    // 17.4 KB
  __shared__ unsigned sH2[256];
  __shared__ float sq[64];
  __shared__ float qp[64][5];
  __shared__ float spp[64][5];
  __shared__ float swt[64];
  __shared__ float sga[4][64];
  __shared__ float sVa[64], sWab[64], sBhh[192];

  // ---- one-time staging ----
#pragma unroll
  for (int g = 0; g < 3; g++) {
    int jl = tid >> 2, part = tid & 3;
    const ushort* src = KWTh + ((size_t)b * G3 + g * 512 + j0 + jl) * 64 + part * 16;
    float* dst = &sKWT[g * 64 + jl][part * 16];
    uint4 u0 = *(const uint4*)src;
    uint4 u1 = *(const uint4*)(src + 8);
    unp2(u0.x, dst); unp2(u0.y, dst + 2); unp2(u0.z, dst + 4); unp2(u0.w, dst + 6);
    unp2(u1.x, dst + 8); unp2(u1.y, dst + 10); unp2(u1.z, dst + 12); unp2(u1.w, dst + 14);
  }
  {
    int s = tid >> 2, part = tid & 3;
    const float* src = ws + UAK_OFF + ((size_t)(b * 64 + s)) * 512 + j0 + part * 16;
    float* dst = &sUAK[s][part * 16];
#pragma unroll
    for (int i = 0; i < 16; i += 4) *(float4*)&dst[i] = *(const float4*)&src[i];
  }
  if (tid < 64) { sVa[tid] = Va_w[j0 + tid]; sWab[tid] = Wa_b[j0 + tid]; }
  if (tid < 192) sBhh[tid] = b_hh[(tid >> 6) * 512 + j0 + (tid & 63)];
  const float va_b = Va_b[0];
  __syncthreads();

  for (int t = 0; t < T; ++t) {
    const float* hcur = ws + HALL_OFF + (size_t)t * B * H + b * H;
    // GIE prefetch (independent of h) issues before the wait
    float gival = 0.f;
    if (tid < 192)
      gival = GIE[((size_t)b * T + t) * G3 + (tid >> 6) * 512 + j0 + (tid & 63)];
    // ---- wait for h_t (dual-flag) ----
    if (t > 0) {
      if (tid == 0) {
        const int* fF = flg + (size_t)(t - 1) * 1024 + b * 32 + 16;
        const int* fS = flg + (size_t)(t - 1) * 1024 + b * 32;
        while (true) {
          if (poll8_l2(fF)) break;
          if (poll8_coh(fS)) break;
        }
      }
    }
    __syncthreads();
    // stage h as packed f16 pairs (float2 per thread, coalesced)
    {
      float2 h2 = *(const float2*)&hcur[2 * tid];
      sH2[tid] = pack_h2(h2.x, h2.y);
    }
    __syncthreads();

    // ---- q slice (coalesced k-major f16) ----
    {
      int jq = tid & 63, kp = tid >> 6;
      const unsigned* wp = WA2T + (size_t)(kp * 64) * 512 + j0 + jq;
      float acc = 0.f;
#pragma unroll 8
      for (int kk = 0; kk < 64; kk++)
        acc = dot2acc(wp[(size_t)kk * 512], sH2[kp * 64 + kk], acc);
      qp[jq][kp] = acc;
    }
    __syncthreads();
    if (tid < 64)
      sq[tid] = qp[tid][0] + qp[tid][1] + qp[tid][2] + qp[tid][3] + sWab[tid];
    __syncthreads();
    // ---- score partials over this WG's 64-j slice ----
    {
      int s = tid >> 2, jc = tid & 3;
      float accs = 0.f;
#pragma unroll
      for (int i = 0; i < 16; i++) {
        int j = jc * 16 + i;
        accs += sVa[j] * fast_tanh(sq[j] + sUAK[s][j]);
      }
      spp[s][jc] = accs;
    }
    __syncthreads();
    if (tid < 64) {
      float v = spp[tid][0] + spp[tid][1] + spp[tid][2] + spp[tid][3];
      if (cb == 0) v += va_b;
      store_coh_f32(SCPT + (((size_t)t * B + b) * 8 + cb) * 64 + tid, v);
    }
    if (tid == 0) {
      asm volatile("s_waitcnt vmcnt(0)" ::: "memory");
      store_plain_i32(flg + (size_t)t * 1024 + b * 32 + 24 + cb, 1);
      store_coh_i32(flg + (size_t)t * 1024 + b * 32 + 8 + cb, 1);
    }

    // ---- gh (coalesced k-major f16), overlaps peers' score phase ----
    float gh = 0.f;
    if (tid < 192) {
      int gate = tid >> 6, lane = tid & 63;
      const unsigned* wp = WHH2T + gate * 512 + j0 + lane;
      float g0 = 0.f, g1 = 0.f;
#pragma unroll 8
      for (int kk = 0; kk < 256; kk += 2) {
        g0 = dot2acc(wp[(size_t)kk * 1536], sH2[kk], g0);
        g1 = dot2acc(wp[(size_t)(kk + 1) * 1536], sH2[kk + 1], g1);
      }
      gh = g0 + g1 + sBhh[tid];
    }
    // ---- wait all 8 score slices of batch b (dual-flag) ----
    if (tid == 0) {
      const int* fF = flg + (size_t)t * 1024 + b * 32 + 24;
      const int* fS = flg + (size_t)t * 1024 + b * 32 + 8;
      while (true) {
        if (poll8_l2(fF)) break;
        if (poll8_coh(fS)) break;
      }
    }
    __syncthreads();
    // ---- direct 8-slice reduce (plain first-touch loads) + softmax ----
    if (tid < 64) {
      const float* sp = SCPT + ((size_t)t * B + b) * 512;
      float v = (sp[tid] + sp[64 + tid]) + (sp[128 + tid] + sp[192 + tid])
              + (sp[256 + tid] + sp[320 + tid]) + (sp[384 + tid] + sp[448 + tid]);
      float m = v;
      for (int o = 32; o; o >>= 1) m = fmaxf(m, __shfl_xor(m, o, 64));
      float e = __expf(v - m);
      float su = e;
      for (int o = 32; o; o >>= 1) su += __shfl_xor(su, o, 64);
      float wt = e / su;
      swt[tid] = wt;
      if (cb == 0) attn_out[((size_t)b * T + t) * S + tid] = wt;
    }
    __syncthreads();
    // ---- gic = KWT . wt (LDS f32) ; combine ----
    if (tid < 192) {
      int gate = tid >> 6, lane = tid & 63;
      float gic = 0.f;
#pragma unroll
      for (int s4 = 0; s4 < 64; s4 += 4) {
        float4 k4 = *(const float4*)&sKWT[tid][s4];
        gic += k4.x * swt[s4] + k4.y * swt[s4 + 1] + k4.z * swt[s4 + 2] + k4.w * swt[s4 + 3];
      }
      float gi = gival + gic;
      if (gate == 0) sga[0][lane] = gi + gh;
      else if (gate == 1) sga[1][lane] = gi + gh;
      else { sga[2][lane] = gi; sga[3][lane] = gh; }
    }
    __syncthreads();
    // ---- GRU update + direct publish ----
    if (tid < 64) {
      float r = fast_sig(sga[0][tid]);
      float z = fast_sig(sga[1][tid]);
      float n = fast_tanh(sga[2][tid] + r * sga[3][tid]);
      float hold = hcur[j0 + tid];
      float hn = (1.f - z) * n + z * hold;
      HBF[((size_t)b * T + t) * H + j0 + tid] = __float2bfloat16(hn);
      if (t < T - 1)
        store_coh_f32(ws + HALL_OFF + (size_t)(t + 1) * B * H + b * H + j0 + tid, hn);
      else
        ht_out[b * H + j0 + tid] = hn;
    }
    if (tid == 0 && t < T - 1) {
      asm volatile("s_waitcnt vmcnt(0)" ::: "memory");
      store_plain_i32(flg + (size_t)t * 1024 + b * 32 + 16 + cb, 1);
      store_coh_i32(flg + (size_t)t * 1024 + b * 32 + cb, 1);
    }
    __syncthreads();   // protect LDS reuse before next iteration
  }
}

// -------- bf16 MFMA out-projection, XCD-sliced bn, fused softmax stats --------
// grid (256,16): bn = (x&7)*32 + (x>>3) -> XCD x%8 owns a contiguous 32-tile
// (4MB) slice of out_w, L2-resident across its 16 bm blocks.
__global__ __launch_bounds__(256) void k_outgemm(
    const __hip_bfloat16* __restrict__ Abf, const __hip_bfloat16* __restrict__ Bbf,
    const float* __restrict__ bias, float* __restrict__ Cmat,
    float* __restrict__ stats) {
  __shared__ __align__(16) short As[128 * 32];
  __shared__ __align__(16) short Bs[128 * 32];
  __shared__ float sredM[2][128];
  __shared__ float sredS[2][128];
  int xv = blockIdx.x;
  int bn = (xv & 7) * 32 + (xv >> 3);
  if (bn >= 250) return;
  int bm = blockIdx.y;
  int tid = threadIdx.x;
  int lane = tid & 63, wv = tid >> 6;
  int wm = wv >> 1, wn = wv & 1;
  int kc = lane >> 4, rl = lane & 15;
  f32x4 acc[4][4] = {};
  int c0 = wv * 128 + lane, c1 = c0 + 64;
  const __hip_bfloat16* ga0 = Abf + (size_t)(bm * 128 + (c0 >> 2)) * 512 + (c0 & 3) * 8;
  const __hip_bfloat16* ga1 = Abf + (size_t)(bm * 128 + (c1 >> 2)) * 512 + (c1 & 3) * 8;
  const __hip_bfloat16* gb0 = Bbf + (size_t)(bn * 128 + (c0 >> 2)) * 512 + (c0 & 3) * 8;
  const __hip_bfloat16* gb1 = Bbf + (size_t)(bn * 128 + (c1 >> 2)) * 512 + (c1 & 3) * 8;
  for (int k0 = 0; k0 < 512; k0 += 32) {
    __syncthreads();
    __builtin_amdgcn_global_load_lds(
        (const __attribute__((address_space(1))) void*)(ga0 + k0),
        (__attribute__((address_space(3))) void*)((char*)As + wv * 2048), 16, 0, 0);
    __builtin_amdgcn_global_load_lds(
        (const __attribute__((address_space(1))) void*)(ga1 + k0),
        (__attribute__((address_space(3))) void*)((char*)As + wv * 2048 + 1024), 16, 0, 0);
    __builtin_amdgcn_global_load_lds(
        (const __attribute__((address_space(1))) void*)(gb0 + k0),
        (__attribute__((address_space(3))) void*)((char*)Bs + wv * 2048), 16, 0, 0);
    __builtin_amdgcn_global_load_lds(
        (const __attribute__((address_space(1))) void*)(gb1 + k0),
        (__attribute__((address_space(3))) void*)((char*)Bs + wv * 2048 + 1024), 16, 0, 0);
    __syncthreads();
    bf16x8 af[4], bfv[4];
#pragma unroll
    for (int f = 0; f < 4; f++) {
      af[f] = *(const bf16x8*)&As[(wm * 64 + f * 16 + rl) * 32 + kc * 8];
      bfv[f] = *(const bf16x8*)&Bs[(wn * 64 + f * 16 + rl) * 32 + kc * 8];
    }
#pragma unroll
    for (int i = 0; i < 4; i++)
#pragma unroll
      for (int j = 0; j < 4; j++)
        acc[i][j] = __builtin_amdgcn_mfma_f32_16x16x32_bf16(af[i], bfv[j], acc[i][j], 0, 0, 0);
  }
  int cl = lane & 15, rg = lane >> 4;
  float bv[4];
#pragma unroll
  for (int j = 0; j < 4; j++) bv[j] = bias[bn * 128 + wn * 64 + j * 16 + cl];
  float vmax[4][4];
#pragma unroll
  for (int i = 0; i < 4; i++) {
    int m = bm * 128 + wm * 64 + i * 16 + rg * 4;
#pragma unroll
    for (int r = 0; r < 4; r++) vmax[i][r] = -1e30f;
#pragma unroll
    for (int j = 0; j < 4; j++) {
      int n = bn * 128 + wn * 64 + j * 16 + cl;
#pragma unroll
      for (int r = 0; r < 4; r++) {
        float val = acc[i][j][r] + bv[j];
        Cmat[(size_t)(m + r) * V + n] = val;
        vmax[i][r] = fmaxf(vmax[i][r], val);
      }
    }
  }
#pragma unroll
  for (int o = 1; o < 16; o <<= 1)
#pragma unroll
    for (int i = 0; i < 4; i++)
#pragma unroll
      for (int r = 0; r < 4; r++)
        vmax[i][r] = fmaxf(vmax[i][r], __shfl_xor(vmax[i][r], o, 64));
  float vsum[4][4] = {};
#pragma unroll
  for (int i = 0; i < 4; i++)
#pragma unroll
    for (int j = 0; j < 4; j++)
#pragma unroll
      for (int r = 0; r < 4; r++)
        vsum[i][r] += __expf(acc[i][j][r] + bv[j] - vmax[i][r]);
#pragma unroll
  for (int o = 1; o < 16; o <<= 1)
#pragma unroll
    for (int i = 0; i < 4; i++)
#pragma unroll
      for (int r = 0; r < 4; r++)
        vsum[i][r] += __shfl_xor(vsum[i][r], o, 64);
  if (cl == 0) {
#pragma unroll
    for (int i = 0; i < 4; i++)
#pragma unroll
      for (int r = 0; r < 4; r++) {
        int rowl = wm * 64 + i * 16 + rg * 4 + r;
        sredM[wn][rowl] = vmax[i][r];
        sredS[wn][rowl] = vsum[i][r];
      }
  }
  __syncthreads();
  if (tid < 128) {
    float m0 = sredM[0][tid], m1 = sredM[1][tid];
    float M = fmaxf(m0, m1);
    float Sv = sredS[0][tid] * __expf(m0 - M) + sredS[1][tid] * __expf(m1 - M);
    float* st = stats + (size_t)(bm * 128 + tid) * 512 + bn * 2;
    st[0] = M; st[1] = Sv;
  }
}

// -------------------- final pass: lse from stats, subtract in-place --------------------
__global__ __launch_bounds__(256) void k_lsm_final(float* __restrict__ Cmat,
                                                   const float* __restrict__ stats) {
  int row = blockIdx.x;
  int tid = threadIdx.x;
  __shared__ float sM[4], sS[4];
  float m = -1e30f, s = 0.f;
  if (tid < 250) {
    float2 v = *(const float2*)&stats[(size_t)row * 512 + tid * 2];
    m = v.x; s = v.y;
  }
  for (int o = 32; o; o >>= 1) {
    float om = __shfl_xor(m, o, 64), os = __shfl_xor(s, o, 64);
    float nm = fmaxf(m, om);
    s = s * __expf(m - nm) + os * __expf(om - nm);
    m = nm;
  }
  if ((tid & 63) == 0) { sM[tid >> 6] = m; sS[tid >> 6] = s; }
  __syncthreads();
  float M = fmaxf(fmaxf(sM[0], sM[1]), fmaxf(sM[2], sM[3]));
  float Ssum = sS[0] * __expf(sM[0] - M) + sS[1] * __expf(sM[1] - M)
             + sS[2] * __expf(sM[2] - M) + sS[3] * __expf(sM[3] - M);
  float lse = M + __logf(Ssum);
  float* p = Cmat + (size_t)row * V;
  for (int i = tid * 4; i < V; i += 1024) {
    float4 v = *(const float4*)&p[i];
    v.x -= lse; v.y -= lse; v.z -= lse; v.w -= lse;
    *(float4*)&p[i] = v;
  }
}

extern "C" void kernel_launch(void* const* d_in, const int* in_sizes, int n_in,
                              void* d_out, int out_size, void* d_ws, size_t ws_size,
                              hipStream_t stream) {
  (void)in_sizes; (void)n_in; (void)out_size; (void)ws_size;
  const float* keys = (const float*)d_in[0];
  const float* ehid = (const float*)d_in[1];
  const int* tgt    = (const int*)d_in[2];
  const float* emb  = (const float*)d_in[4];
  const float* Wa_w = (const float*)d_in[5];
  const float* Wa_b = (const float*)d_in[6];
  const float* Ua_w = (const float*)d_in[7];
  const float* Ua_b = (const float*)d_in[8];
  const float* Va_w = (const float*)d_in[9];
  const float* Va_b = (const float*)d_in[10];
  const float* W_ih = (const float*)d_in[11];
  const float* W_hh = (const float*)d_in[12];
  const float* b_ih = (const float*)d_in[13];
  const float* b_hh = (const float*)d_in[14];
  const float* out_w = (const float*)d_in[15];
  const float* out_b = (const float*)d_in[16];
  float* ws = (float*)d_ws;
  float* out = (float*)d_out;
  float* logits = out;                              // [B,T,V]
  float* ht_out = out + (size_t)B * T * V;          // [1,B,H]
  float* attn_out = ht_out + (size_t)B * H;         // [B,T,S]

  // consolidated prep (init + f16 convs + packs)
  hipLaunchKernelGGL(k_prep, dim3(6144), dim3(256), 0, stream,
                     ehid, tgt, keys, emb, Ua_w, W_ih, Wa_w, W_hh, ws);
  // UAK = keys @ Ua_w.T + Ua_b  (f16 MFMA)
  hipLaunchKernelGGL(k_mfma128, dim3(4, 16), dim3(256), 0, stream,
                     (const ushort*)(ws + KEYSH_OFF), (const ushort*)(ws + UAWH_OFF),
                     Ua_b, ws + UAK_OFF, 512);
  // GIE = emb[tokens] @ W_ih_lo.T + b_ih  (f16 MFMA)
  hipLaunchKernelGGL(k_mfma128, dim3(12, 16), dim3(256), 0, stream,
                     (const ushort*)(ws + GEH_OFF), (const ushort*)(ws + WLOH_OFF),
                     b_ih, ws + GIE_OFF, G3);
  // KWT (f16 out) = W_ih_ctx @ keys_b^T  (f16 MFMA, per b)
  hipLaunchKernelGGL(k_mfma_kwt, dim3(12, 32), dim3(256), 0, stream,
                     (const ushort*)(ws + WCTXH_OFF), (const ushort*)(ws + KEYSH_OFF),
                     (ushort*)(ws + KWTH_OFF));
  // persistent recurrence (writes ht_out at final step)
  hipLaunchKernelGGL(k_recur, dim3(256), dim3(256), 0, stream,
                     Wa_b, Va_w, Va_b, b_hh,
                     (const unsigned*)(ws + WA2T_OFF), (const unsigned*)(ws + WHH2T_OFF),
                     ws, attn_out, ht_out);
  // bf16 out_w copy into the (now dead) precompute region
  hipLaunchKernelGGL(k_conv_outw, dim3((V * H / 4 + 255) / 256), dim3(256), 0, stream,
                     out_w, (ushort*)(ws + OWBF_OFF), V * H / 4);
  hipLaunchKernelGGL(k_outgemm, dim3(256, 16), dim3(256), 0, stream,
                     (const __hip_bfloat16*)(ws + HBF_OFF),
                     (const __hip_bfloat16*)(ws + OWBF_OFF), out_b, logits,
                     ws + STATS_OFF);
  hipLaunchKernelGGL(k_lsm_final, dim3(BT), dim3(256), 0, stream,
                     logits, ws + STATS_OFF);
}